// Round 3
// baseline (2167.150 us; speedup 1.0000x reference)
//
#include <hip/hip_runtime.h>
#include <hip/hip_bf16.h>
#include <stdint.h>

#define N_NODES 50000
#define N_EDGES 200000
#define NODE_F 64
#define EDGE_F 16
#define HID 32
#define LAT 16

__global__ void k_zero(float* __restrict__ p, int n) {
  int t = blockIdx.x*256 + threadIdx.x;
  if (t < n) p[t] = 0.f;
}

// h = relu(x @ W + b)   x:[N,64] f32, W:[64,32] f32 -> h f32 [N,32]
__global__ void k_lin_in(const float* __restrict__ x,
                         const float* __restrict__ W,
                         const float* __restrict__ b,
                         float* __restrict__ h) {
  __shared__ float Ws[NODE_F*HID];
  __shared__ float bs[HID];
  for (int i = threadIdx.x; i < NODE_F*HID; i += 256) Ws[i] = W[i];
  if (threadIdx.x < HID) bs[threadIdx.x] = b[threadIdx.x];
  __syncthreads();
  int t = blockIdx.x*256 + threadIdx.x;
  if (t >= N_NODES*HID) return;
  int n = t >> 5, o = t & 31;
  const float4* xp = (const float4*)(x + (size_t)n*NODE_F);
  float acc = bs[o];
  #pragma unroll
  for (int j = 0; j < NODE_F/4; j++) {
    float4 v = xp[j];
    acc = fmaf(v.x, Ws[(4*j+0)*HID+o], acc);
    acc = fmaf(v.y, Ws[(4*j+1)*HID+o], acc);
    acc = fmaf(v.z, Ws[(4*j+2)*HID+o], acc);
    acc = fmaf(v.w, Ws[(4*j+3)*HID+o], acc);
  }
  h[t] = fmaxf(acc, 0.f);
}

// Fused per-edge: he = relu(ea@W1+b1); msg[e,o] = sum_h xs[h]*(sum_k he[k]*w2[k,h*32+o] + b2[h*32+o])
// scatter-add msg into agg[dst], count into cnt[dst]. 2 edges per thread; w2 staged fp32 in 4 phases.
__global__ __launch_bounds__(256) void k_msg(const float* __restrict__ hin,
                                             const float* __restrict__ ea,
                                             const int* __restrict__ ei,
                                             const float* __restrict__ w1,
                                             const float* __restrict__ b1,
                                             const float* __restrict__ w2,
                                             const float* __restrict__ b2,
                                             float* __restrict__ agg,
                                             float* __restrict__ cnt) {
  __shared__ float w2s[8*1024];    // 32 KB: 8 k-rows of w2 [32,1024]
  __shared__ float b2s[HID*HID];   // 4 KB
  __shared__ float w1s[EDGE_F*HID];// 2 KB
  __shared__ float b1s[HID];
  const int tid = threadIdx.x;
  const float4* w2g4 = (const float4*)w2;
  float4* w2s4 = (float4*)w2s;
  for (int i = tid; i < HID*HID; i += 256) b2s[i] = b2[i];
  for (int i = tid; i < EDGE_F*HID; i += 256) w1s[i] = w1[i];
  if (tid < HID) b1s[tid] = b1[tid];
  for (int i = tid; i < 2048; i += 256) w2s4[i] = w2g4[i];   // phase 0 rows
  __syncthreads();

  int e0 = blockIdx.x*512 + tid;
  int ev[2] = { e0, e0 + 256 };
  float xs[2][HID], her[2][HID], acc[2][HID];
  int dst[2]; bool val[2];
  #pragma unroll
  for (int u = 0; u < 2; u++) {
    val[u] = ev[u] < N_EDGES;
    int idx = val[u] ? ev[u] : 0;
    int src = ei[idx];
    int d   = ei[N_EDGES + idx];
    src = min(max(src, 0), N_NODES-1);
    dst[u] = min(max(d, 0), N_NODES-1);
    // edge MLP
    float eav[EDGE_F];
    const float4* ep = (const float4*)(ea + (size_t)idx*EDGE_F);
    #pragma unroll
    for (int j = 0; j < EDGE_F/4; j++) {
      float4 v = ep[j];
      eav[4*j]=v.x; eav[4*j+1]=v.y; eav[4*j+2]=v.z; eav[4*j+3]=v.w;
    }
    #pragma unroll 4
    for (int k = 0; k < HID; k++) {
      float a = b1s[k];
      #pragma unroll
      for (int j = 0; j < EDGE_F; j++) a = fmaf(eav[j], w1s[j*HID+k], a);
      her[u][k] = val[u] ? fmaxf(a, 0.f) : 0.f;
    }
    const float4* xp = (const float4*)(hin + (size_t)src*HID);
    #pragma unroll
    for (int i = 0; i < HID/4; i++) {
      float4 v = xp[i];
      xs[u][4*i]=v.x; xs[u][4*i+1]=v.y; xs[u][4*i+2]=v.z; xs[u][4*i+3]=v.w;
      if (!val[u]) { xs[u][4*i]=0; xs[u][4*i+1]=0; xs[u][4*i+2]=0; xs[u][4*i+3]=0; }
    }
    #pragma unroll
    for (int o = 0; o < HID; o++) acc[u][o] = 0.f;
  }

  for (int p = 0; p < 4; p++) {
    if (p > 0) {
      __syncthreads();
      for (int i = tid; i < 2048; i += 256) w2s4[i] = w2g4[p*2048 + i];
      __syncthreads();
    }
    for (int kk = 0; kk < 8; kk++) {
      float hk0 = her[0][p*8 + kk];
      float hk1 = her[1][p*8 + kk];
      const float4* wrow = (const float4*)(w2s + kk*1024);
      #pragma unroll 4
      for (int h = 0; h < HID; h++) {
        float p0 = hk0 * xs[0][h];
        float p1 = hk1 * xs[1][h];
        const float4* wp = wrow + h*8;
        #pragma unroll
        for (int q = 0; q < 8; q++) {
          float4 w = wp[q];
          acc[0][4*q+0] = fmaf(p0, w.x, acc[0][4*q+0]);
          acc[0][4*q+1] = fmaf(p0, w.y, acc[0][4*q+1]);
          acc[0][4*q+2] = fmaf(p0, w.z, acc[0][4*q+2]);
          acc[0][4*q+3] = fmaf(p0, w.w, acc[0][4*q+3]);
          acc[1][4*q+0] = fmaf(p1, w.x, acc[1][4*q+0]);
          acc[1][4*q+1] = fmaf(p1, w.y, acc[1][4*q+1]);
          acc[1][4*q+2] = fmaf(p1, w.z, acc[1][4*q+2]);
          acc[1][4*q+3] = fmaf(p1, w.w, acc[1][4*q+3]);
        }
      }
    }
  }

  // bias term: acc[o] += sum_h xs[h]*b2[h*32+o]; then scatter
  #pragma unroll
  for (int u = 0; u < 2; u++) {
    if (!val[u]) continue;
    #pragma unroll 4
    for (int h = 0; h < HID; h++) {
      float xh = xs[u][h];
      const float4* bp = (const float4*)(b2s + h*HID);
      #pragma unroll
      for (int q = 0; q < 8; q++) {
        float4 v = bp[q];
        acc[u][4*q+0] = fmaf(xh, v.x, acc[u][4*q+0]);
        acc[u][4*q+1] = fmaf(xh, v.y, acc[u][4*q+1]);
        acc[u][4*q+2] = fmaf(xh, v.z, acc[u][4*q+2]);
        acc[u][4*q+3] = fmaf(xh, v.w, acc[u][4*q+3]);
      }
    }
    float* ap = agg + (size_t)dst[u]*HID;
    #pragma unroll
    for (int o = 0; o < HID; o++) atomicAdd(ap + o, acc[u][o]);
    atomicAdd(cnt + dst[u], 1.f);
  }
}

// hout = relu(agg/max(cnt,1) + hin @ root_w + root_b)
__global__ void k_combine(const float* __restrict__ agg, const float* __restrict__ cnt,
                          const float* __restrict__ hin,
                          const float* __restrict__ rw,
                          const float* __restrict__ rb,
                          float* __restrict__ hout) {
  __shared__ float rws[HID*HID];
  __shared__ float rbs[HID];
  for (int i = threadIdx.x; i < HID*HID; i += 256) rws[i] = rw[i];
  if (threadIdx.x < HID) rbs[threadIdx.x] = rb[threadIdx.x];
  __syncthreads();
  int t = blockIdx.x*256 + threadIdx.x;
  if (t >= N_NODES*HID) return;
  int n = t >> 5, o = t & 31;
  float a = agg[t] / fmaxf(cnt[n], 1.f) + rbs[o];
  const float4* hp = (const float4*)(hin + (size_t)n*HID);
  #pragma unroll
  for (int j = 0; j < HID/4; j++) {
    float4 v = hp[j];
    a = fmaf(v.x, rws[(4*j+0)*HID+o], a);
    a = fmaf(v.y, rws[(4*j+1)*HID+o], a);
    a = fmaf(v.z, rws[(4*j+2)*HID+o], a);
    a = fmaf(v.w, rws[(4*j+3)*HID+o], a);
  }
  hout[t] = fmaxf(a, 0.f);
}

// out = (relu((h@lo_w+lo_b)@d1_w+d1_b))@d2_w+d2_b   (no relu on z)
__global__ void k_decoder(const float* __restrict__ h,
                          const float* __restrict__ lo_w, const float* __restrict__ lo_b,
                          const float* __restrict__ d1_w, const float* __restrict__ d1_b,
                          const float* __restrict__ d2_w, const float* __restrict__ d2_b,
                          float* __restrict__ out) {
  __shared__ float lows[HID*LAT], lobs[LAT], d1s[LAT*HID], d1bs[HID], d2s[HID*NODE_F], d2bs[NODE_F];
  for (int i = threadIdx.x; i < HID*LAT; i += 256) lows[i] = lo_w[i];
  for (int i = threadIdx.x; i < LAT; i += 256) lobs[i] = lo_b[i];
  for (int i = threadIdx.x; i < LAT*HID; i += 256) d1s[i] = d1_w[i];
  for (int i = threadIdx.x; i < HID; i += 256) d1bs[i] = d1_b[i];
  for (int i = threadIdx.x; i < HID*NODE_F; i += 256) d2s[i] = d2_w[i];
  for (int i = threadIdx.x; i < NODE_F; i += 256) d2bs[i] = d2_b[i];
  __syncthreads();
  int n = blockIdx.x*256 + threadIdx.x;
  if (n >= N_NODES) return;
  float hr[HID];
  const float4* hp = (const float4*)(h + (size_t)n*HID);
  #pragma unroll
  for (int i = 0; i < HID/4; i++) { float4 v = hp[i]; hr[4*i]=v.x; hr[4*i+1]=v.y; hr[4*i+2]=v.z; hr[4*i+3]=v.w; }
  float z[LAT];
  #pragma unroll
  for (int o = 0; o < LAT; o++) {
    float a = lobs[o];
    #pragma unroll
    for (int j = 0; j < HID; j++) a = fmaf(hr[j], lows[j*LAT+o], a);
    z[o] = a;
  }
  float d[HID];
  #pragma unroll
  for (int o = 0; o < HID; o++) {
    float a = d1bs[o];
    #pragma unroll
    for (int j = 0; j < LAT; j++) a = fmaf(z[j], d1s[j*HID+o], a);
    d[o] = fmaxf(a, 0.f);
  }
  float* op = out + (size_t)n*NODE_F;
  #pragma unroll 8
  for (int o = 0; o < NODE_F; o++) {
    float a = d2bs[o];
    #pragma unroll
    for (int j = 0; j < HID; j++) a = fmaf(d[j], d2s[j*NODE_F+o], a);
    op[o] = a;
  }
}

extern "C" void kernel_launch(void* const* d_in, const int* in_sizes, int n_in,
                              void* d_out, int out_size, void* d_ws, size_t ws_size,
                              hipStream_t stream) {
  const float* x   = (const float*)d_in[0];
  const int*   ei  = (const int*)d_in[1];
  const float* ea  = (const float*)d_in[2];
  const float* liw = (const float*)d_in[3];
  const float* lib = (const float*)d_in[4];
  const float* ew1 = (const float*)d_in[5];
  const float* eb1 = (const float*)d_in[6];
  const float* ew2 = (const float*)d_in[7];
  const float* eb2 = (const float*)d_in[8];
  const float* rw  = (const float*)d_in[9];
  const float* rb  = (const float*)d_in[10];
  const float* low = (const float*)d_in[11];
  const float* lob = (const float*)d_in[12];
  const float* d1w = (const float*)d_in[13];
  const float* d1b = (const float*)d_in[14];
  const float* d2w = (const float*)d_in[15];
  const float* d2b = (const float*)d_in[16];
  float* out = (float*)d_out;

  float* h0  = (float*)d_ws;
  float* h1  = h0  + (size_t)N_NODES*HID;
  float* agg = h1  + (size_t)N_NODES*HID;
  float* cnt = agg + (size_t)N_NODES*HID;   // contiguous with agg for one-shot zero

  k_lin_in<<<(N_NODES*HID + 255)/256, 256, 0, stream>>>(x, liw, lib, h0);

  float* hin = h0; float* hout = h1;
  for (int i = 0; i < 3; i++) {
    k_zero<<<(N_NODES*HID + N_NODES + 255)/256, 256, 0, stream>>>(agg, N_NODES*HID + N_NODES);
    k_msg<<<(N_EDGES + 511)/512, 256, 0, stream>>>(hin, ea, ei,
        ew1 + i*EDGE_F*HID, eb1 + i*HID,
        ew2 + (size_t)i*HID*HID*HID, eb2 + (size_t)i*HID*HID, agg, cnt);
    k_combine<<<(N_NODES*HID + 255)/256, 256, 0, stream>>>(agg, cnt, hin,
        rw + i*HID*HID, rb + i*HID, hout);
    float* t = hin; hin = hout; hout = t;
  }

  k_decoder<<<(N_NODES + 255)/256, 256, 0, stream>>>(hin, low, lob, d1w, d1b, d2w, d2b, out);
}

// Round 4
// 1407.497 us; speedup vs baseline: 1.5397x; 1.5397x over previous
//
#include <hip/hip_runtime.h>
#include <hip/hip_bf16.h>
#include <stdint.h>

#define N_NODES 50000
#define N_EDGES 200000
#define NODE_F 64
#define EDGE_F 16
#define HID 32
#define LAT 16

__global__ void k_zero(float* __restrict__ p, int n) {
  int t = blockIdx.x*256 + threadIdx.x;
  if (t < n) p[t] = 0.f;
}

// h = relu(x @ W + b)   x:[N,64] f32, W:[64,32] f32 -> h f32 [N,32]
__global__ void k_lin_in(const float* __restrict__ x,
                         const float* __restrict__ W,
                         const float* __restrict__ b,
                         float* __restrict__ h) {
  __shared__ float Ws[NODE_F*HID];
  __shared__ float bs[HID];
  for (int i = threadIdx.x; i < NODE_F*HID; i += 256) Ws[i] = W[i];
  if (threadIdx.x < HID) bs[threadIdx.x] = b[threadIdx.x];
  __syncthreads();
  int t = blockIdx.x*256 + threadIdx.x;
  if (t >= N_NODES*HID) return;
  int n = t >> 5, o = t & 31;
  const float4* xp = (const float4*)(x + (size_t)n*NODE_F);
  float acc = bs[o];
  #pragma unroll
  for (int j = 0; j < NODE_F/4; j++) {
    float4 v = xp[j];
    acc = fmaf(v.x, Ws[(4*j+0)*HID+o], acc);
    acc = fmaf(v.y, Ws[(4*j+1)*HID+o], acc);
    acc = fmaf(v.z, Ws[(4*j+2)*HID+o], acc);
    acc = fmaf(v.w, Ws[(4*j+3)*HID+o], acc);
  }
  h[t] = fmaxf(acc, 0.f);
}

// Fused per-edge NNConv message with o-split parallelism:
// 64 edges/block, 4 threads/edge, each thread computes 8 of 32 outputs.
// he = relu(ea@W1+b1) recomputed per thread (registers); w2 staged in LDS
// in 4 phases of 8 k-rows (32 KB). Grid = 3125 blocks (200000/64).
__global__ __launch_bounds__(256) void k_msg(const float* __restrict__ hin,
                                             const float* __restrict__ ea,
                                             const int* __restrict__ ei,
                                             const float* __restrict__ w1,
                                             const float* __restrict__ b1,
                                             const float* __restrict__ w2,
                                             const float* __restrict__ b2,
                                             float* __restrict__ agg,
                                             float* __restrict__ cnt) {
  __shared__ float w2s[8*1024];    // 32 KB: 8 k-rows of w2 [32][1024]
  __shared__ float b2s[HID*HID];   // 4 KB
  __shared__ float w1s[EDGE_F*HID];// 2 KB
  __shared__ float b1s[HID];
  const int tid = threadIdx.x;
  const int el  = tid >> 2;        // edge within block
  const int oc  = tid & 3;         // o-chunk: outputs oc*8 .. oc*8+7

  const float4* w2g4 = (const float4*)w2;
  float4* w2s4 = (float4*)w2s;
  for (int i = tid; i < HID*HID; i += 256) b2s[i] = b2[i];
  for (int i = tid; i < EDGE_F*HID; i += 256) w1s[i] = w1[i];
  if (tid < HID) b1s[tid] = b1[tid];
  for (int i = tid; i < 2048; i += 256) w2s4[i] = w2g4[i];   // phase 0
  __syncthreads();

  const int e = blockIdx.x*64 + el;          // grid is exact: 200000 = 3125*64
  int src = ei[e];
  int dst = ei[N_EDGES + e];
  src = min(max(src, 0), N_NODES-1);
  dst = min(max(dst, 0), N_NODES-1);

  // edge MLP (each of the 4 threads per edge computes full he[32])
  float eav[EDGE_F];
  {
    const float4* ep = (const float4*)(ea + (size_t)e*EDGE_F);
    #pragma unroll
    for (int j = 0; j < EDGE_F/4; j++) {
      float4 v = ep[j];
      eav[4*j]=v.x; eav[4*j+1]=v.y; eav[4*j+2]=v.z; eav[4*j+3]=v.w;
    }
  }
  float he_[HID];
  #pragma unroll 4
  for (int k = 0; k < HID; k++) {
    float a = b1s[k];
    #pragma unroll
    for (int j = 0; j < EDGE_F; j++) a = fmaf(eav[j], w1s[j*HID+k], a);
    he_[k] = fmaxf(a, 0.f);
  }
  float xs_[HID];
  {
    const float4* xp = (const float4*)(hin + (size_t)src*HID);
    #pragma unroll
    for (int i = 0; i < HID/4; i++) {
      float4 v = xp[i];
      xs_[4*i]=v.x; xs_[4*i+1]=v.y; xs_[4*i+2]=v.z; xs_[4*i+3]=v.w;
    }
  }
  float acc[8];
  #pragma unroll
  for (int q = 0; q < 8; q++) acc[q] = 0.f;

  for (int p = 0; p < 4; p++) {
    if (p > 0) {
      __syncthreads();
      for (int i = tid; i < 2048; i += 256) w2s4[i] = w2g4[p*2048 + i];
      __syncthreads();
    }
    #pragma unroll
    for (int kk = 0; kk < 8; kk++) {
      float hk = he_[p*8 + kk];
      const float4* wrow = (const float4*)(w2s + kk*1024 + oc*8);
      #pragma unroll 4
      for (int h = 0; h < HID; h++) {
        float pm = hk * xs_[h];
        float4 wa = wrow[h*8 + 0];
        float4 wb = wrow[h*8 + 1];
        acc[0] = fmaf(pm, wa.x, acc[0]);
        acc[1] = fmaf(pm, wa.y, acc[1]);
        acc[2] = fmaf(pm, wa.z, acc[2]);
        acc[3] = fmaf(pm, wa.w, acc[3]);
        acc[4] = fmaf(pm, wb.x, acc[4]);
        acc[5] = fmaf(pm, wb.y, acc[5]);
        acc[6] = fmaf(pm, wb.z, acc[6]);
        acc[7] = fmaf(pm, wb.w, acc[7]);
      }
    }
  }

  // bias term: acc[q] += sum_h xs[h]*b2[h*32 + oc*8 + q]
  #pragma unroll 4
  for (int h = 0; h < HID; h++) {
    float xh = xs_[h];
    const float4* bp = (const float4*)(b2s + h*HID + oc*8);
    float4 ba = bp[0];
    float4 bb = bp[1];
    acc[0] = fmaf(xh, ba.x, acc[0]);
    acc[1] = fmaf(xh, ba.y, acc[1]);
    acc[2] = fmaf(xh, ba.z, acc[2]);
    acc[3] = fmaf(xh, ba.w, acc[3]);
    acc[4] = fmaf(xh, bb.x, acc[4]);
    acc[5] = fmaf(xh, bb.y, acc[5]);
    acc[6] = fmaf(xh, bb.z, acc[6]);
    acc[7] = fmaf(xh, bb.w, acc[7]);
  }

  float* ap = agg + (size_t)dst*HID + oc*8;
  #pragma unroll
  for (int q = 0; q < 8; q++) atomicAdd(ap + q, acc[q]);
  if (oc == 0) atomicAdd(cnt + dst, 1.f);
}

// hout = relu(agg/max(cnt,1) + hin @ root_w + root_b)
__global__ void k_combine(const float* __restrict__ agg, const float* __restrict__ cnt,
                          const float* __restrict__ hin,
                          const float* __restrict__ rw,
                          const float* __restrict__ rb,
                          float* __restrict__ hout) {
  __shared__ float rws[HID*HID];
  __shared__ float rbs[HID];
  for (int i = threadIdx.x; i < HID*HID; i += 256) rws[i] = rw[i];
  if (threadIdx.x < HID) rbs[threadIdx.x] = rb[threadIdx.x];
  __syncthreads();
  int t = blockIdx.x*256 + threadIdx.x;
  if (t >= N_NODES*HID) return;
  int n = t >> 5, o = t & 31;
  float a = agg[t] / fmaxf(cnt[n], 1.f) + rbs[o];
  const float4* hp = (const float4*)(hin + (size_t)n*HID);
  #pragma unroll
  for (int j = 0; j < HID/4; j++) {
    float4 v = hp[j];
    a = fmaf(v.x, rws[(4*j+0)*HID+o], a);
    a = fmaf(v.y, rws[(4*j+1)*HID+o], a);
    a = fmaf(v.z, rws[(4*j+2)*HID+o], a);
    a = fmaf(v.w, rws[(4*j+3)*HID+o], a);
  }
  hout[t] = fmaxf(a, 0.f);
}

// out = (relu((h@lo_w+lo_b)@d1_w+d1_b))@d2_w+d2_b   (no relu on z)
__global__ void k_decoder(const float* __restrict__ h,
                          const float* __restrict__ lo_w, const float* __restrict__ lo_b,
                          const float* __restrict__ d1_w, const float* __restrict__ d1_b,
                          const float* __restrict__ d2_w, const float* __restrict__ d2_b,
                          float* __restrict__ out) {
  __shared__ float lows[HID*LAT], lobs[LAT], d1s[LAT*HID], d1bs[HID], d2s[HID*NODE_F], d2bs[NODE_F];
  for (int i = threadIdx.x; i < HID*LAT; i += 256) lows[i] = lo_w[i];
  for (int i = threadIdx.x; i < LAT; i += 256) lobs[i] = lo_b[i];
  for (int i = threadIdx.x; i < LAT*HID; i += 256) d1s[i] = d1_w[i];
  for (int i = threadIdx.x; i < HID; i += 256) d1bs[i] = d1_b[i];
  for (int i = threadIdx.x; i < HID*NODE_F; i += 256) d2s[i] = d2_w[i];
  for (int i = threadIdx.x; i < NODE_F; i += 256) d2bs[i] = d2_b[i];
  __syncthreads();
  int n = blockIdx.x*256 + threadIdx.x;
  if (n >= N_NODES) return;
  float hr[HID];
  const float4* hp = (const float4*)(h + (size_t)n*HID);
  #pragma unroll
  for (int i = 0; i < HID/4; i++) { float4 v = hp[i]; hr[4*i]=v.x; hr[4*i+1]=v.y; hr[4*i+2]=v.z; hr[4*i+3]=v.w; }
  float z[LAT];
  #pragma unroll
  for (int o = 0; o < LAT; o++) {
    float a = lobs[o];
    #pragma unroll
    for (int j = 0; j < HID; j++) a = fmaf(hr[j], lows[j*LAT+o], a);
    z[o] = a;
  }
  float d[HID];
  #pragma unroll
  for (int o = 0; o < HID; o++) {
    float a = d1bs[o];
    #pragma unroll
    for (int j = 0; j < LAT; j++) a = fmaf(z[j], d1s[j*HID+o], a);
    d[o] = fmaxf(a, 0.f);
  }
  float* op = out + (size_t)n*NODE_F;
  #pragma unroll 8
  for (int o = 0; o < NODE_F; o++) {
    float a = d2bs[o];
    #pragma unroll
    for (int j = 0; j < HID; j++) a = fmaf(d[j], d2s[j*NODE_F+o], a);
    op[o] = a;
  }
}

extern "C" void kernel_launch(void* const* d_in, const int* in_sizes, int n_in,
                              void* d_out, int out_size, void* d_ws, size_t ws_size,
                              hipStream_t stream) {
  const float* x   = (const float*)d_in[0];
  const int*   ei  = (const int*)d_in[1];
  const float* ea  = (const float*)d_in[2];
  const float* liw = (const float*)d_in[3];
  const float* lib = (const float*)d_in[4];
  const float* ew1 = (const float*)d_in[5];
  const float* eb1 = (const float*)d_in[6];
  const float* ew2 = (const float*)d_in[7];
  const float* eb2 = (const float*)d_in[8];
  const float* rw  = (const float*)d_in[9];
  const float* rb  = (const float*)d_in[10];
  const float* low = (const float*)d_in[11];
  const float* lob = (const float*)d_in[12];
  const float* d1w = (const float*)d_in[13];
  const float* d1b = (const float*)d_in[14];
  const float* d2w = (const float*)d_in[15];
  const float* d2b = (const float*)d_in[16];
  float* out = (float*)d_out;

  float* h0  = (float*)d_ws;
  float* h1  = h0  + (size_t)N_NODES*HID;
  float* agg = h1  + (size_t)N_NODES*HID;
  float* cnt = agg + (size_t)N_NODES*HID;   // contiguous with agg for one-shot zero

  k_lin_in<<<(N_NODES*HID + 255)/256, 256, 0, stream>>>(x, liw, lib, h0);

  float* hin = h0; float* hout = h1;
  for (int i = 0; i < 3; i++) {
    k_zero<<<(N_NODES*HID + N_NODES + 255)/256, 256, 0, stream>>>(agg, N_NODES*HID + N_NODES);
    k_msg<<<N_EDGES/64, 256, 0, stream>>>(hin, ea, ei,
        ew1 + i*EDGE_F*HID, eb1 + i*HID,
        ew2 + (size_t)i*HID*HID*HID, eb2 + (size_t)i*HID*HID, agg, cnt);
    k_combine<<<(N_NODES*HID + 255)/256, 256, 0, stream>>>(agg, cnt, hin,
        rw + i*HID*HID, rb + i*HID, hout);
    float* t = hin; hin = hout; hout = t;
  }

  k_decoder<<<(N_NODES + 255)/256, 256, 0, stream>>>(hin, low, lob, d1w, d1b, d2w, d2b, out);
}

// Round 5
// 1124.128 us; speedup vs baseline: 1.9279x; 1.2521x over previous
//
#include <hip/hip_runtime.h>
#include <hip/hip_bf16.h>
#include <stdint.h>

#define N_NODES 50000
#define N_EDGES 200000
#define NODE_F 64
#define EDGE_F 16
#define HID 32
#define LAT 16

__global__ void k_zero_int(int* __restrict__ p, int n) {
  int t = blockIdx.x*256 + threadIdx.x;
  if (t < n) p[t] = 0;
}

// --- CSR construction (once per call) ---
__global__ void k_hist(const int* __restrict__ ei, int* __restrict__ deg) {
  int t = blockIdx.x*256 + threadIdx.x;
  if (t >= N_EDGES) return;
  int d = ei[N_EDGES + t];
  d = min(max(d, 0), N_NODES-1);
  atomicAdd(&deg[d], 1);
}

// single-block exclusive scan of deg[50000] -> off; also zeroes cursor
__global__ __launch_bounds__(1024) void k_scan(const int* __restrict__ deg,
                                               int* __restrict__ off,
                                               int* __restrict__ cursor) {
  __shared__ int s[1024];
  const int tid = threadIdx.x;
  const int base = tid*49;             // 1024*49 = 50176 >= 50000
  int loc[49]; int T = 0;
  #pragma unroll 7
  for (int j = 0; j < 49; j++) {
    int i = base + j;
    int d = (i < N_NODES) ? deg[i] : 0;
    loc[j] = T; T += d;
  }
  s[tid] = T; __syncthreads();
  for (int ofs = 1; ofs < 1024; ofs <<= 1) {
    int v = (tid >= ofs) ? s[tid-ofs] : 0;
    __syncthreads();
    s[tid] += v;
    __syncthreads();
  }
  int excl = s[tid] - T;
  #pragma unroll 7
  for (int j = 0; j < 49; j++) {
    int i = base + j;
    if (i < N_NODES) { off[i] = excl + loc[j]; cursor[i] = 0; }
  }
  if (tid == 1023) off[N_NODES] = s[1023];
}

__global__ void k_scatter(const int* __restrict__ ei, const int* __restrict__ off,
                          int* __restrict__ cursor, int* __restrict__ elist) {
  int t = blockIdx.x*256 + threadIdx.x;
  if (t >= N_EDGES) return;
  int d = ei[N_EDGES + t];
  d = min(max(d, 0), N_NODES-1);
  int pos = atomicAdd(&cursor[d], 1);
  elist[off[d] + pos] = t;
}

// h = relu(x @ W + b)   x:[N,64] f32, W:[64,32] f32 -> h f32 [N,32]
__global__ void k_lin_in(const float* __restrict__ x,
                         const float* __restrict__ W,
                         const float* __restrict__ b,
                         float* __restrict__ h) {
  __shared__ float Ws[NODE_F*HID];
  __shared__ float bs[HID];
  for (int i = threadIdx.x; i < NODE_F*HID; i += 256) Ws[i] = W[i];
  if (threadIdx.x < HID) bs[threadIdx.x] = b[threadIdx.x];
  __syncthreads();
  int t = blockIdx.x*256 + threadIdx.x;
  if (t >= N_NODES*HID) return;
  int n = t >> 5, o = t & 31;
  const float4* xp = (const float4*)(x + (size_t)n*NODE_F);
  float acc = bs[o];
  #pragma unroll
  for (int j = 0; j < NODE_F/4; j++) {
    float4 v = xp[j];
    acc = fmaf(v.x, Ws[(4*j+0)*HID+o], acc);
    acc = fmaf(v.y, Ws[(4*j+1)*HID+o], acc);
    acc = fmaf(v.z, Ws[(4*j+2)*HID+o], acc);
    acc = fmaf(v.w, Ws[(4*j+3)*HID+o], acc);
  }
  h[t] = fmaxf(acc, 0.f);
}

// msg[e,o] = sum_h xs[h]*(sum_k he[k]*w2[k,h*32+o] + b2[h*32+o]), written to msg buffer.
// 2 threads/edge (oc in {0,1}, 16 outputs each); 256 edges/block (512 thr);
// w2 staged in LDS in 2 phases of 16 k-rows (64 KB = WG max); w1/b1/b2 from global (L1-hot).
__global__ __launch_bounds__(512) void k_msg(const float* __restrict__ hin,
                                             const float* __restrict__ ea,
                                             const int* __restrict__ ei,
                                             const float* __restrict__ w1,
                                             const float* __restrict__ b1,
                                             const float* __restrict__ w2,
                                             const float* __restrict__ b2,
                                             float* __restrict__ msg) {
  __shared__ float w2s[16*1024];   // 64 KB
  const int tid = threadIdx.x;
  const int el  = tid >> 1;        // edge within block (0..255)
  const int oc  = tid & 1;         // output half: oc*16 .. oc*16+15

  const float4* w2g4 = (const float4*)w2;
  float4* w2s4 = (float4*)w2s;
  for (int i = tid; i < 4096; i += 512) w2s4[i] = w2g4[i];   // phase 0: rows 0..15
  // edge setup while staging is in flight
  const int e = blockIdx.x*256 + el;
  const bool valid = e < N_EDGES;
  const int eidx = valid ? e : 0;
  int src = ei[eidx];
  src = min(max(src, 0), N_NODES-1);

  float eav[EDGE_F];
  {
    const float4* ep = (const float4*)(ea + (size_t)eidx*EDGE_F);
    #pragma unroll
    for (int j = 0; j < EDGE_F/4; j++) {
      float4 v = ep[j];
      eav[4*j]=v.x; eav[4*j+1]=v.y; eav[4*j+2]=v.z; eav[4*j+3]=v.w;
    }
  }
  float he_[HID];
  #pragma unroll 4
  for (int k = 0; k < HID; k++) {
    float a = b1[k];
    #pragma unroll
    for (int j = 0; j < EDGE_F; j++) a = fmaf(eav[j], w1[j*HID+k], a);
    he_[k] = fmaxf(a, 0.f);
  }
  float xs_[HID];
  {
    const float4* xp = (const float4*)(hin + (size_t)src*HID);
    #pragma unroll
    for (int i = 0; i < HID/4; i++) {
      float4 v = xp[i];
      xs_[4*i]=v.x; xs_[4*i+1]=v.y; xs_[4*i+2]=v.z; xs_[4*i+3]=v.w;
    }
  }
  float acc[16];
  #pragma unroll
  for (int q = 0; q < 16; q++) acc[q] = 0.f;

  __syncthreads();
  // phase 0: k rows 0..15
  #pragma unroll
  for (int kk = 0; kk < 16; kk++) {
    float hk = he_[kk];
    const float* wrow = w2s + kk*1024 + oc*16;
    for (int h = 0; h < HID; h++) {     // rolled: keep code size in I$
      float pm = hk * xs_[h];
      const float4* wp = (const float4*)(wrow + h*32);
      float4 w0 = wp[0], w1v = wp[1], w2v = wp[2], w3 = wp[3];
      acc[ 0] = fmaf(pm, w0.x,  acc[ 0]);
      acc[ 1] = fmaf(pm, w0.y,  acc[ 1]);
      acc[ 2] = fmaf(pm, w0.z,  acc[ 2]);
      acc[ 3] = fmaf(pm, w0.w,  acc[ 3]);
      acc[ 4] = fmaf(pm, w1v.x, acc[ 4]);
      acc[ 5] = fmaf(pm, w1v.y, acc[ 5]);
      acc[ 6] = fmaf(pm, w1v.z, acc[ 6]);
      acc[ 7] = fmaf(pm, w1v.w, acc[ 7]);
      acc[ 8] = fmaf(pm, w2v.x, acc[ 8]);
      acc[ 9] = fmaf(pm, w2v.y, acc[ 9]);
      acc[10] = fmaf(pm, w2v.z, acc[10]);
      acc[11] = fmaf(pm, w2v.w, acc[11]);
      acc[12] = fmaf(pm, w3.x,  acc[12]);
      acc[13] = fmaf(pm, w3.y,  acc[13]);
      acc[14] = fmaf(pm, w3.z,  acc[14]);
      acc[15] = fmaf(pm, w3.w,  acc[15]);
    }
  }
  __syncthreads();
  for (int i = tid; i < 4096; i += 512) w2s4[i] = w2g4[4096 + i];  // phase 1: rows 16..31
  __syncthreads();
  #pragma unroll
  for (int kk = 0; kk < 16; kk++) {
    float hk = he_[16 + kk];
    const float* wrow = w2s + kk*1024 + oc*16;
    for (int h = 0; h < HID; h++) {
      float pm = hk * xs_[h];
      const float4* wp = (const float4*)(wrow + h*32);
      float4 w0 = wp[0], w1v = wp[1], w2v = wp[2], w3 = wp[3];
      acc[ 0] = fmaf(pm, w0.x,  acc[ 0]);
      acc[ 1] = fmaf(pm, w0.y,  acc[ 1]);
      acc[ 2] = fmaf(pm, w0.z,  acc[ 2]);
      acc[ 3] = fmaf(pm, w0.w,  acc[ 3]);
      acc[ 4] = fmaf(pm, w1v.x, acc[ 4]);
      acc[ 5] = fmaf(pm, w1v.y, acc[ 5]);
      acc[ 6] = fmaf(pm, w1v.z, acc[ 6]);
      acc[ 7] = fmaf(pm, w1v.w, acc[ 7]);
      acc[ 8] = fmaf(pm, w2v.x, acc[ 8]);
      acc[ 9] = fmaf(pm, w2v.y, acc[ 9]);
      acc[10] = fmaf(pm, w2v.z, acc[10]);
      acc[11] = fmaf(pm, w2v.w, acc[11]);
      acc[12] = fmaf(pm, w3.x,  acc[12]);
      acc[13] = fmaf(pm, w3.y,  acc[13]);
      acc[14] = fmaf(pm, w3.z,  acc[14]);
      acc[15] = fmaf(pm, w3.w,  acc[15]);
    }
  }

  if (!valid) return;
  // bias: acc[q] += sum_h xs[h]*b2[h*32 + oc*16 + q]   (b2 4 KB, L1-hot)
  for (int h = 0; h < HID; h++) {
    float xh = xs_[h];
    const float4* bp = (const float4*)(b2 + h*HID + oc*16);
    float4 b0 = bp[0], b1v = bp[1], b2v = bp[2], b3 = bp[3];
    acc[ 0] = fmaf(xh, b0.x,  acc[ 0]);
    acc[ 1] = fmaf(xh, b0.y,  acc[ 1]);
    acc[ 2] = fmaf(xh, b0.z,  acc[ 2]);
    acc[ 3] = fmaf(xh, b0.w,  acc[ 3]);
    acc[ 4] = fmaf(xh, b1v.x, acc[ 4]);
    acc[ 5] = fmaf(xh, b1v.y, acc[ 5]);
    acc[ 6] = fmaf(xh, b1v.z, acc[ 6]);
    acc[ 7] = fmaf(xh, b1v.w, acc[ 7]);
    acc[ 8] = fmaf(xh, b2v.x, acc[ 8]);
    acc[ 9] = fmaf(xh, b2v.y, acc[ 9]);
    acc[10] = fmaf(xh, b2v.z, acc[10]);
    acc[11] = fmaf(xh, b2v.w, acc[11]);
    acc[12] = fmaf(xh, b3.x,  acc[12]);
    acc[13] = fmaf(xh, b3.y,  acc[13]);
    acc[14] = fmaf(xh, b3.z,  acc[14]);
    acc[15] = fmaf(xh, b3.w,  acc[15]);
  }
  float4* mp = (float4*)(msg + (size_t)e*HID + oc*16);
  mp[0] = make_float4(acc[0],  acc[1],  acc[2],  acc[3]);
  mp[1] = make_float4(acc[4],  acc[5],  acc[6],  acc[7]);
  mp[2] = make_float4(acc[8],  acc[9],  acc[10], acc[11]);
  mp[3] = make_float4(acc[12], acc[13], acc[14], acc[15]);
}

// hout = relu( (sum_{e in CSR[n]} msg[e]) / max(deg,1) + hin @ root_w + root_b )
__global__ void k_gather(const float* __restrict__ msg,
                         const int* __restrict__ off, const int* __restrict__ elist,
                         const float* __restrict__ hin,
                         const float* __restrict__ rw,
                         const float* __restrict__ rb,
                         float* __restrict__ hout) {
  __shared__ float rws[HID*HID];
  __shared__ float rbs[HID];
  for (int i = threadIdx.x; i < HID*HID; i += 256) rws[i] = rw[i];
  if (threadIdx.x < HID) rbs[threadIdx.x] = rb[threadIdx.x];
  __syncthreads();
  int t = blockIdx.x*256 + threadIdx.x;
  if (t >= N_NODES*HID) return;
  int n = t >> 5, o = t & 31;
  int s0 = off[n], s1 = off[n+1];
  float sum = 0.f;
  for (int j = s0; j < s1; j++)
    sum += msg[(size_t)elist[j]*HID + o];
  float a = sum / fmaxf((float)(s1 - s0), 1.f) + rbs[o];
  const float4* hp = (const float4*)(hin + (size_t)n*HID);
  #pragma unroll
  for (int j = 0; j < HID/4; j++) {
    float4 v = hp[j];
    a = fmaf(v.x, rws[(4*j+0)*HID+o], a);
    a = fmaf(v.y, rws[(4*j+1)*HID+o], a);
    a = fmaf(v.z, rws[(4*j+2)*HID+o], a);
    a = fmaf(v.w, rws[(4*j+3)*HID+o], a);
  }
  hout[t] = fmaxf(a, 0.f);
}

// out = (relu((h@lo_w+lo_b)@d1_w+d1_b))@d2_w+d2_b   (no relu on z)
__global__ void k_decoder(const float* __restrict__ h,
                          const float* __restrict__ lo_w, const float* __restrict__ lo_b,
                          const float* __restrict__ d1_w, const float* __restrict__ d1_b,
                          const float* __restrict__ d2_w, const float* __restrict__ d2_b,
                          float* __restrict__ out) {
  __shared__ float lows[HID*LAT], lobs[LAT], d1s[LAT*HID], d1bs[HID], d2s[HID*NODE_F], d2bs[NODE_F];
  for (int i = threadIdx.x; i < HID*LAT; i += 256) lows[i] = lo_w[i];
  for (int i = threadIdx.x; i < LAT; i += 256) lobs[i] = lo_b[i];
  for (int i = threadIdx.x; i < LAT*HID; i += 256) d1s[i] = d1_w[i];
  for (int i = threadIdx.x; i < HID; i += 256) d1bs[i] = d1_b[i];
  for (int i = threadIdx.x; i < HID*NODE_F; i += 256) d2s[i] = d2_w[i];
  for (int i = threadIdx.x; i < NODE_F; i += 256) d2bs[i] = d2_b[i];
  __syncthreads();
  int n = blockIdx.x*256 + threadIdx.x;
  if (n >= N_NODES) return;
  float hr[HID];
  const float4* hp = (const float4*)(h + (size_t)n*HID);
  #pragma unroll
  for (int i = 0; i < HID/4; i++) { float4 v = hp[i]; hr[4*i]=v.x; hr[4*i+1]=v.y; hr[4*i+2]=v.z; hr[4*i+3]=v.w; }
  float z[LAT];
  #pragma unroll
  for (int o = 0; o < LAT; o++) {
    float a = lobs[o];
    #pragma unroll
    for (int j = 0; j < HID; j++) a = fmaf(hr[j], lows[j*LAT+o], a);
    z[o] = a;
  }
  float d[HID];
  #pragma unroll
  for (int o = 0; o < HID; o++) {
    float a = d1bs[o];
    #pragma unroll
    for (int j = 0; j < LAT; j++) a = fmaf(z[j], d1s[j*HID+o], a);
    d[o] = fmaxf(a, 0.f);
  }
  float* op = out + (size_t)n*NODE_F;
  #pragma unroll 8
  for (int o = 0; o < NODE_F; o++) {
    float a = d2bs[o];
    #pragma unroll
    for (int j = 0; j < HID; j++) a = fmaf(d[j], d2s[j*NODE_F+o], a);
    op[o] = a;
  }
}

extern "C" void kernel_launch(void* const* d_in, const int* in_sizes, int n_in,
                              void* d_out, int out_size, void* d_ws, size_t ws_size,
                              hipStream_t stream) {
  const float* x   = (const float*)d_in[0];
  const int*   ei  = (const int*)d_in[1];
  const float* ea  = (const float*)d_in[2];
  const float* liw = (const float*)d_in[3];
  const float* lib = (const float*)d_in[4];
  const float* ew1 = (const float*)d_in[5];
  const float* eb1 = (const float*)d_in[6];
  const float* ew2 = (const float*)d_in[7];
  const float* eb2 = (const float*)d_in[8];
  const float* rw  = (const float*)d_in[9];
  const float* rb  = (const float*)d_in[10];
  const float* low = (const float*)d_in[11];
  const float* lob = (const float*)d_in[12];
  const float* d1w = (const float*)d_in[13];
  const float* d1b = (const float*)d_in[14];
  const float* d2w = (const float*)d_in[15];
  const float* d2b = (const float*)d_in[16];
  float* out = (float*)d_out;

  float* h0   = (float*)d_ws;                         // 1.6M f
  float* h1   = h0  + (size_t)N_NODES*HID;            // 1.6M f
  float* msg  = h1  + (size_t)N_NODES*HID;            // 6.4M f
  int*  deg   = (int*)(msg + (size_t)N_EDGES*HID);    // 50k
  int*  off   = deg + N_NODES;                        // 50k+1
  int*  cursor= off + N_NODES + 16;                   // 50k
  int*  elist = cursor + N_NODES;                     // 200k

  // CSR build (once per call)
  k_zero_int<<<(N_NODES + 255)/256, 256, 0, stream>>>(deg, N_NODES);
  k_hist<<<(N_EDGES + 255)/256, 256, 0, stream>>>(ei, deg);
  k_scan<<<1, 1024, 0, stream>>>(deg, off, cursor);
  k_scatter<<<(N_EDGES + 255)/256, 256, 0, stream>>>(ei, off, cursor, elist);

  k_lin_in<<<(N_NODES*HID + 255)/256, 256, 0, stream>>>(x, liw, lib, h0);

  float* hin = h0; float* hout = h1;
  for (int i = 0; i < 3; i++) {
    k_msg<<<(N_EDGES + 255)/256, 512, 0, stream>>>(hin, ea, ei,
        ew1 + i*EDGE_F*HID, eb1 + i*HID,
        ew2 + (size_t)i*HID*HID*HID, eb2 + (size_t)i*HID*HID, msg);
    k_gather<<<(N_NODES*HID + 255)/256, 256, 0, stream>>>(msg, off, elist, hin,
        rw + i*HID*HID, rb + i*HID, hout);
    float* t = hin; hin = hout; hout = t;
  }

  k_decoder<<<(N_NODES + 255)/256, 256, 0, stream>>>(hin, low, lob, d1w, d1b, d2w, d2b, out);
}

// Round 6
// 554.819 us; speedup vs baseline: 3.9061x; 2.0261x over previous
//
#include <hip/hip_runtime.h>
#include <hip/hip_bf16.h>
#include <stdint.h>

#define N_NODES 50000
#define N_EDGES 200000
#define NODE_F 64
#define EDGE_F 16
#define HID 32
#define LAT 16
#define KTOT 1056   // 1024 + 32 (b2 folded in as 33rd K-tile)

typedef __attribute__((ext_vector_type(8))) short short8;   // 8 bf16 = 4 VGPR
typedef __attribute__((ext_vector_type(4))) float f32x4;

static __device__ __forceinline__ unsigned short bfbits(float f) {
  union { __hip_bfloat16 h; unsigned short s; } c; c.h = __float2bfloat16(f); return c.s;
}
static __device__ __forceinline__ unsigned pkbf(float a, float b) {
  return (unsigned)bfbits(a) | ((unsigned)bfbits(b) << 16);
}
union AFrag { short8 v; unsigned u[4]; };

__global__ void k_zero_int(int* __restrict__ p, int n) {
  int t = blockIdx.x*256 + threadIdx.x;
  if (t < n) p[t] = 0;
}

// --- CSR construction (once per call) ---
__global__ void k_hist(const int* __restrict__ ei, int* __restrict__ deg) {
  int t = blockIdx.x*256 + threadIdx.x;
  if (t >= N_EDGES) return;
  int d = ei[N_EDGES + t];
  d = min(max(d, 0), N_NODES-1);
  atomicAdd(&deg[d], 1);
}

__global__ __launch_bounds__(1024) void k_scan(const int* __restrict__ deg,
                                               int* __restrict__ off,
                                               int* __restrict__ cursor) {
  __shared__ int s[1024];
  const int tid = threadIdx.x;
  const int base = tid*49;
  int loc[49]; int T = 0;
  #pragma unroll 7
  for (int j = 0; j < 49; j++) {
    int i = base + j;
    int d = (i < N_NODES) ? deg[i] : 0;
    loc[j] = T; T += d;
  }
  s[tid] = T; __syncthreads();
  for (int ofs = 1; ofs < 1024; ofs <<= 1) {
    int v = (tid >= ofs) ? s[tid-ofs] : 0;
    __syncthreads();
    s[tid] += v;
    __syncthreads();
  }
  int excl = s[tid] - T;
  #pragma unroll 7
  for (int j = 0; j < 49; j++) {
    int i = base + j;
    if (i < N_NODES) { off[i] = excl + loc[j]; cursor[i] = 0; }
  }
  if (tid == 1023) off[N_NODES] = s[1023];
}

__global__ void k_scatter(const int* __restrict__ ei, const int* __restrict__ off,
                          int* __restrict__ cursor, int* __restrict__ elist) {
  int t = blockIdx.x*256 + threadIdx.x;
  if (t >= N_EDGES) return;
  int d = ei[N_EDGES + t];
  d = min(max(d, 0), N_NODES-1);
  int pos = atomicAdd(&cursor[d], 1);
  elist[off[d] + pos] = t;
}

// w2t[l][o][k*32+h] = bf16( k<32 ? w2[l][k][h*32+o] : b2[l][h*32+o] )
__global__ void k_prep_w2t(const float* __restrict__ ew2, const float* __restrict__ eb2,
                           unsigned short* __restrict__ w2t) {
  int g = blockIdx.x*256 + threadIdx.x;          // 3*32*1056 = 101376 threads exactly
  int l = g / (HID*KTOT);
  int r = g % (HID*KTOT);
  int o = r / KTOT;
  int kg = r % KTOT;
  int k = kg >> 5, h = kg & 31;
  float v = (k < 32) ? ew2[(size_t)l*32768 + k*1024 + h*32 + o]
                     : eb2[(size_t)l*1024 + h*32 + o];
  w2t[g] = bfbits(v);
}

// h = relu(x @ W + b)
__global__ void k_lin_in(const float* __restrict__ x,
                         const float* __restrict__ W,
                         const float* __restrict__ b,
                         float* __restrict__ h) {
  __shared__ float Ws[NODE_F*HID];
  __shared__ float bs[HID];
  for (int i = threadIdx.x; i < NODE_F*HID; i += 256) Ws[i] = W[i];
  if (threadIdx.x < HID) bs[threadIdx.x] = b[threadIdx.x];
  __syncthreads();
  int t = blockIdx.x*256 + threadIdx.x;
  if (t >= N_NODES*HID) return;
  int n = t >> 5, o = t & 31;
  const float4* xp = (const float4*)(x + (size_t)n*NODE_F);
  float acc = bs[o];
  #pragma unroll
  for (int j = 0; j < NODE_F/4; j++) {
    float4 v = xp[j];
    acc = fmaf(v.x, Ws[(4*j+0)*HID+o], acc);
    acc = fmaf(v.y, Ws[(4*j+1)*HID+o], acc);
    acc = fmaf(v.z, Ws[(4*j+2)*HID+o], acc);
    acc = fmaf(v.w, Ws[(4*j+3)*HID+o], acc);
  }
  h[t] = fmaxf(acc, 0.f);
}

// MFMA msg kernel: msg[E,32] = P[E,1056] @ W2R[1056,32], P[e, kk*32+h] = he[e,kk]*xs[e,h]
// (he[e,32]=1 folds bias). Block = 256 thr = 4 waves; 128 edges/block (32/wave, 2 M-tiles).
// A-frag built on the fly from LDS he/xs; B-frag read from global w2t (L1/L2-hot).
__global__ __launch_bounds__(256) void k_msg(const float* __restrict__ hin,
                                             const float* __restrict__ ea,
                                             const int* __restrict__ ei,
                                             const float* __restrict__ w1,
                                             const float* __restrict__ b1,
                                             const unsigned short* __restrict__ w2tl,
                                             float* __restrict__ msg) {
  __shared__ float sHE[128*36];   // he[e][0..32], rows padded to 36 (bank shift 4)
  __shared__ float sXS[128*36];   // xs[e][0..31]
  const int tid = threadIdx.x;
  const int be  = blockIdx.x*128;

  // --- stage he (edge MLP) ---
  {
    int el = tid >> 1, half = tid & 1;
    int e = be + el; e = min(e, N_EDGES-1);
    float eav[EDGE_F];
    const float4* ep = (const float4*)(ea + (size_t)e*EDGE_F);
    #pragma unroll
    for (int j = 0; j < 4; j++) {
      float4 v = ep[j];
      eav[4*j]=v.x; eav[4*j+1]=v.y; eav[4*j+2]=v.z; eav[4*j+3]=v.w;
    }
    #pragma unroll 4
    for (int k2 = 0; k2 < 16; k2++) {
      int k = half*16 + k2;
      float a = b1[k];
      #pragma unroll
      for (int j = 0; j < EDGE_F; j++) a = fmaf(eav[j], w1[j*HID+k], a);
      sHE[el*36 + k] = fmaxf(a, 0.f);
    }
    if (tid < 128) sHE[tid*36 + 32] = 1.0f;   // bias K-tile
  }
  // --- stage xs (gather source features) ---
  for (int i = tid; i < 128*8; i += 256) {
    int el = i >> 3, q = i & 7;
    int e = be + el; e = min(e, N_EDGES-1);
    int src = ei[e];
    src = min(max(src, 0), N_NODES-1);
    float4 v = ((const float4*)(hin + (size_t)src*HID))[q];
    ((float4*)(sXS + el*36))[q] = v;
  }
  __syncthreads();

  const int wv   = tid >> 6;          // wave 0..3
  const int lane = tid & 63;
  const int nn   = lane & 15;         // A-row (edge) during build; D-col (output) at store
  const int quad = lane >> 4;
  const int q8   = quad * 8;
  const int eb0  = wv*32;             // local edge rows for M-tile 0
  const int eb1  = wv*32 + 16;        // M-tile 1

  // per-lane xs8 for both M-tiles
  float4 x0a, x0b, x1a, x1b;
  {
    const float4* p0 = (const float4*)(sXS + (eb0+nn)*36 + q8);
    x0a = p0[0]; x0b = p0[1];
    const float4* p1 = (const float4*)(sXS + (eb1+nn)*36 + q8);
    x1a = p1[0]; x1b = p1[1];
  }

  f32x4 c00 = {0.f,0.f,0.f,0.f}, c01 = c00, c10 = c00, c11 = c00;
  const unsigned short* brow0 = w2tl + (unsigned)nn*KTOT + q8;
  const unsigned short* brow1 = brow0 + 16*KTOT;

  for (int kk = 0; kk < 33; kk++) {
    short8 b0 = *(const short8*)(brow0 + kk*32);
    short8 b1f = *(const short8*)(brow1 + kk*32);
    float hk0 = sHE[(eb0+nn)*36 + kk];
    float hk1 = sHE[(eb1+nn)*36 + kk];
    AFrag a0, a1;
    a0.u[0] = pkbf(hk0*x0a.x, hk0*x0a.y);
    a0.u[1] = pkbf(hk0*x0a.z, hk0*x0a.w);
    a0.u[2] = pkbf(hk0*x0b.x, hk0*x0b.y);
    a0.u[3] = pkbf(hk0*x0b.z, hk0*x0b.w);
    a1.u[0] = pkbf(hk1*x1a.x, hk1*x1a.y);
    a1.u[1] = pkbf(hk1*x1a.z, hk1*x1a.w);
    a1.u[2] = pkbf(hk1*x1b.x, hk1*x1b.y);
    a1.u[3] = pkbf(hk1*x1b.z, hk1*x1b.w);
    c00 = __builtin_amdgcn_mfma_f32_16x16x32_bf16(a0.v, b0,  c00, 0, 0, 0);
    c01 = __builtin_amdgcn_mfma_f32_16x16x32_bf16(a0.v, b1f, c01, 0, 0, 0);
    c10 = __builtin_amdgcn_mfma_f32_16x16x32_bf16(a1.v, b0,  c10, 0, 0, 0);
    c11 = __builtin_amdgcn_mfma_f32_16x16x32_bf16(a1.v, b1f, c11, 0, 0, 0);
  }

  // store: D row = quad*4 + r (edge within tile), col = nn (output)
  #pragma unroll
  for (int r = 0; r < 4; r++) {
    int e0 = be + eb0 + quad*4 + r;
    if (e0 < N_EDGES) {
      msg[(size_t)e0*HID +      nn] = c00[r];
      msg[(size_t)e0*HID + 16 + nn] = c01[r];
    }
    int e1 = be + eb1 + quad*4 + r;
    if (e1 < N_EDGES) {
      msg[(size_t)e1*HID +      nn] = c10[r];
      msg[(size_t)e1*HID + 16 + nn] = c11[r];
    }
  }
}

// hout = relu( (sum_{e in CSR[n]} msg[e]) / max(deg,1) + hin @ root_w + root_b )
__global__ void k_gather(const float* __restrict__ msg,
                         const int* __restrict__ off, const int* __restrict__ elist,
                         const float* __restrict__ hin,
                         const float* __restrict__ rw,
                         const float* __restrict__ rb,
                         float* __restrict__ hout) {
  __shared__ float rws[HID*HID];
  __shared__ float rbs[HID];
  for (int i = threadIdx.x; i < HID*HID; i += 256) rws[i] = rw[i];
  if (threadIdx.x < HID) rbs[threadIdx.x] = rb[threadIdx.x];
  __syncthreads();
  int t = blockIdx.x*256 + threadIdx.x;
  if (t >= N_NODES*HID) return;
  int n = t >> 5, o = t & 31;
  int s0 = off[n], s1 = off[n+1];
  float sum = 0.f;
  for (int j = s0; j < s1; j++)
    sum += msg[(size_t)elist[j]*HID + o];
  float a = sum / fmaxf((float)(s1 - s0), 1.f) + rbs[o];
  const float4* hp = (const float4*)(hin + (size_t)n*HID);
  #pragma unroll
  for (int j = 0; j < HID/4; j++) {
    float4 v = hp[j];
    a = fmaf(v.x, rws[(4*j+0)*HID+o], a);
    a = fmaf(v.y, rws[(4*j+1)*HID+o], a);
    a = fmaf(v.z, rws[(4*j+2)*HID+o], a);
    a = fmaf(v.w, rws[(4*j+3)*HID+o], a);
  }
  hout[t] = fmaxf(a, 0.f);
}

// out = (relu((h@lo_w+lo_b)@d1_w+d1_b))@d2_w+d2_b   (no relu on z)
__global__ void k_decoder(const float* __restrict__ h,
                          const float* __restrict__ lo_w, const float* __restrict__ lo_b,
                          const float* __restrict__ d1_w, const float* __restrict__ d1_b,
                          const float* __restrict__ d2_w, const float* __restrict__ d2_b,
                          float* __restrict__ out) {
  __shared__ float lows[HID*LAT], lobs[LAT], d1s[LAT*HID], d1bs[HID], d2s[HID*NODE_F], d2bs[NODE_F];
  for (int i = threadIdx.x; i < HID*LAT; i += 256) lows[i] = lo_w[i];
  for (int i = threadIdx.x; i < LAT; i += 256) lobs[i] = lo_b[i];
  for (int i = threadIdx.x; i < LAT*HID; i += 256) d1s[i] = d1_w[i];
  for (int i = threadIdx.x; i < HID; i += 256) d1bs[i] = d1_b[i];
  for (int i = threadIdx.x; i < HID*NODE_F; i += 256) d2s[i] = d2_w[i];
  for (int i = threadIdx.x; i < NODE_F; i += 256) d2bs[i] = d2_b[i];
  __syncthreads();
  int n = blockIdx.x*256 + threadIdx.x;
  if (n >= N_NODES) return;
  float hr[HID];
  const float4* hp = (const float4*)(h + (size_t)n*HID);
  #pragma unroll
  for (int i = 0; i < HID/4; i++) { float4 v = hp[i]; hr[4*i]=v.x; hr[4*i+1]=v.y; hr[4*i+2]=v.z; hr[4*i+3]=v.w; }
  float z[LAT];
  #pragma unroll
  for (int o = 0; o < LAT; o++) {
    float a = lobs[o];
    #pragma unroll
    for (int j = 0; j < HID; j++) a = fmaf(hr[j], lows[j*LAT+o], a);
    z[o] = a;
  }
  float d[HID];
  #pragma unroll
  for (int o = 0; o < HID; o++) {
    float a = d1bs[o];
    #pragma unroll
    for (int j = 0; j < LAT; j++) a = fmaf(z[j], d1s[j*HID+o], a);
    d[o] = fmaxf(a, 0.f);
  }
  float* op = out + (size_t)n*NODE_F;
  #pragma unroll 8
  for (int o = 0; o < NODE_F; o++) {
    float a = d2bs[o];
    #pragma unroll
    for (int j = 0; j < HID; j++) a = fmaf(d[j], d2s[j*NODE_F+o], a);
    op[o] = a;
  }
}

extern "C" void kernel_launch(void* const* d_in, const int* in_sizes, int n_in,
                              void* d_out, int out_size, void* d_ws, size_t ws_size,
                              hipStream_t stream) {
  const float* x   = (const float*)d_in[0];
  const int*   ei  = (const int*)d_in[1];
  const float* ea  = (const float*)d_in[2];
  const float* liw = (const float*)d_in[3];
  const float* lib = (const float*)d_in[4];
  const float* ew1 = (const float*)d_in[5];
  const float* eb1 = (const float*)d_in[6];
  const float* ew2 = (const float*)d_in[7];
  const float* eb2 = (const float*)d_in[8];
  const float* rw  = (const float*)d_in[9];
  const float* rb  = (const float*)d_in[10];
  const float* low = (const float*)d_in[11];
  const float* lob = (const float*)d_in[12];
  const float* d1w = (const float*)d_in[13];
  const float* d1b = (const float*)d_in[14];
  const float* d2w = (const float*)d_in[15];
  const float* d2b = (const float*)d_in[16];
  float* out = (float*)d_out;

  float* h0   = (float*)d_ws;                          // 1.6M f
  float* h1   = h0  + (size_t)N_NODES*HID;             // 1.6M f
  float* msg  = h1  + (size_t)N_NODES*HID;             // 6.4M f
  int*  deg   = (int*)(msg + (size_t)N_EDGES*HID);     // 50k
  int*  off   = deg + N_NODES;                         // 50k+1 (alloc 50016)
  int*  cursor= off + N_NODES + 16;                    // 50k
  int*  elist = cursor + N_NODES;                      // 200k
  unsigned short* w2t = (unsigned short*)(elist + N_EDGES);  // 3*32*1056 bf16

  // one-time prep
  k_prep_w2t<<<(3*HID*KTOT)/256, 256, 0, stream>>>(ew2, eb2, w2t);
  k_zero_int<<<(N_NODES + 255)/256, 256, 0, stream>>>(deg, N_NODES);
  k_hist<<<(N_EDGES + 255)/256, 256, 0, stream>>>(ei, deg);
  k_scan<<<1, 1024, 0, stream>>>(deg, off, cursor);
  k_scatter<<<(N_EDGES + 255)/256, 256, 0, stream>>>(ei, off, cursor, elist);

  k_lin_in<<<(N_NODES*HID + 255)/256, 256, 0, stream>>>(x, liw, lib, h0);

  float* hin = h0; float* hout = h1;
  for (int i = 0; i < 3; i++) {
    k_msg<<<(N_EDGES + 127)/128, 256, 0, stream>>>(hin, ea, ei,
        ew1 + i*EDGE_F*HID, eb1 + i*HID,
        w2t + (size_t)i*HID*KTOT, msg);
    k_gather<<<(N_NODES*HID + 255)/256, 256, 0, stream>>>(msg, off, elist, hin,
        rw + i*HID*HID, rb + i*HID, hout);
    float* t = hin; hin = hout; hout = t;
  }

  k_decoder<<<(N_NODES + 255)/256, 256, 0, stream>>>(hin, low, lob, d1w, d1b, d2w, d2b, out);
}

// Round 7
// 408.511 us; speedup vs baseline: 5.3050x; 1.3581x over previous
//
#include <hip/hip_runtime.h>
#include <hip/hip_bf16.h>
#include <stdint.h>

#define N_NODES 50000
#define N_EDGES 200000
#define NODE_F 64
#define EDGE_F 16
#define HID 32
#define LAT 16
#define KTOT 1056   // 1024 + 32 (b2 folded in as 33rd K-tile)
#define SCAN_BLOCKS 196   // 196*256 = 50176 >= 50000

typedef __attribute__((ext_vector_type(8))) short short8;   // 8 bf16 = 4 VGPR
typedef __attribute__((ext_vector_type(4))) float f32x4;

static __device__ __forceinline__ unsigned short bfbits(float f) {
  union { __hip_bfloat16 h; unsigned short s; } c; c.h = __float2bfloat16(f); return c.s;
}
static __device__ __forceinline__ unsigned pkbf(float a, float b) {
  return (unsigned)bfbits(a) | ((unsigned)bfbits(b) << 16);
}
union AFrag { short8 v; unsigned u[4]; };

__global__ void k_zero_int(int* __restrict__ p, int n) {
  int t = blockIdx.x*256 + threadIdx.x;
  if (t < n) p[t] = 0;
}

// --- CSR construction (once per call) ---
__global__ void k_hist(const int* __restrict__ ei, int* __restrict__ deg) {
  int t = blockIdx.x*256 + threadIdx.x;
  if (t >= N_EDGES) return;
  int d = ei[N_EDGES + t];
  d = min(max(d, 0), N_NODES-1);
  atomicAdd(&deg[d], 1);
}

// Stage 1: per-block inclusive scan of 256 deg entries; local-exclusive to off,
// block total to bsum. No per-thread arrays -> no scratch spill.
__global__ __launch_bounds__(256) void k_scan1(const int* __restrict__ deg,
                                               int* __restrict__ off,
                                               int* __restrict__ bsum) {
  __shared__ int s[256];
  const int tid = threadIdx.x;
  const int t = blockIdx.x*256 + tid;
  int d = (t < N_NODES) ? deg[t] : 0;
  s[tid] = d; __syncthreads();
  int v = d;
  #pragma unroll
  for (int ofs = 1; ofs < 256; ofs <<= 1) {
    int w = (tid >= ofs) ? s[tid-ofs] : 0;
    __syncthreads();
    v += w; s[tid] = v;
    __syncthreads();
  }
  if (t < N_NODES) off[t] = v - d;            // local exclusive
  if (tid == 255) bsum[blockIdx.x] = v;       // block total
}

// Stage 2: single block scans bsum[SCAN_BLOCKS] -> exclusive block offsets
__global__ __launch_bounds__(256) void k_scan2(int* __restrict__ bsum) {
  __shared__ int s[256];
  const int tid = threadIdx.x;
  int d = (tid < SCAN_BLOCKS) ? bsum[tid] : 0;
  s[tid] = d; __syncthreads();
  int v = d;
  #pragma unroll
  for (int ofs = 1; ofs < 256; ofs <<= 1) {
    int w = (tid >= ofs) ? s[tid-ofs] : 0;
    __syncthreads();
    v += w; s[tid] = v;
    __syncthreads();
  }
  if (tid < SCAN_BLOCKS) bsum[tid] = v - d;   // exclusive
}

// Stage 3: apply block offsets, zero cursor, set off[N] (total == N_EDGES exactly)
__global__ void k_scan3(int* __restrict__ off, const int* __restrict__ bsum,
                        int* __restrict__ cursor) {
  int t = blockIdx.x*256 + threadIdx.x;
  if (t < N_NODES) {
    off[t] += bsum[t >> 8];
    cursor[t] = 0;
  }
  if (t == 0) off[N_NODES] = N_EDGES;
}

__global__ void k_scatter(const int* __restrict__ ei, const int* __restrict__ off,
                          int* __restrict__ cursor, int* __restrict__ elist) {
  int t = blockIdx.x*256 + threadIdx.x;
  if (t >= N_EDGES) return;
  int d = ei[N_EDGES + t];
  d = min(max(d, 0), N_NODES-1);
  int pos = atomicAdd(&cursor[d], 1);
  elist[off[d] + pos] = t;
}

// w2t[l][o][k*32+h] = bf16( k<32 ? w2[l][k][h*32+o] : b2[l][h*32+o] )
__global__ void k_prep_w2t(const float* __restrict__ ew2, const float* __restrict__ eb2,
                           unsigned short* __restrict__ w2t) {
  int g = blockIdx.x*256 + threadIdx.x;          // 3*32*1056 = 101376 threads exactly
  int l = g / (HID*KTOT);
  int r = g % (HID*KTOT);
  int o = r / KTOT;
  int kg = r % KTOT;
  int k = kg >> 5, h = kg & 31;
  float v = (k < 32) ? ew2[(size_t)l*32768 + k*1024 + h*32 + o]
                     : eb2[(size_t)l*1024 + h*32 + o];
  w2t[g] = bfbits(v);
}

// h = relu(x @ W + b)
__global__ void k_lin_in(const float* __restrict__ x,
                         const float* __restrict__ W,
                         const float* __restrict__ b,
                         float* __restrict__ h) {
  __shared__ float Ws[NODE_F*HID];
  __shared__ float bs[HID];
  for (int i = threadIdx.x; i < NODE_F*HID; i += 256) Ws[i] = W[i];
  if (threadIdx.x < HID) bs[threadIdx.x] = b[threadIdx.x];
  __syncthreads();
  int t = blockIdx.x*256 + threadIdx.x;
  if (t >= N_NODES*HID) return;
  int n = t >> 5, o = t & 31;
  const float4* xp = (const float4*)(x + (size_t)n*NODE_F);
  float acc = bs[o];
  #pragma unroll
  for (int j = 0; j < NODE_F/4; j++) {
    float4 v = xp[j];
    acc = fmaf(v.x, Ws[(4*j+0)*HID+o], acc);
    acc = fmaf(v.y, Ws[(4*j+1)*HID+o], acc);
    acc = fmaf(v.z, Ws[(4*j+2)*HID+o], acc);
    acc = fmaf(v.w, Ws[(4*j+3)*HID+o], acc);
  }
  h[t] = fmaxf(acc, 0.f);
}

// MFMA msg kernel: msg[E,32] = P[E,1056] @ W2R[1056,32], P[e, kk*32+h] = he[e,kk]*xs[e,h]
// (he[e,32]=1 folds bias). Block = 256 thr = 4 waves; 128 edges/block (32/wave, 2 M-tiles).
__global__ __launch_bounds__(256) void k_msg(const float* __restrict__ hin,
                                             const float* __restrict__ ea,
                                             const int* __restrict__ ei,
                                             const float* __restrict__ w1,
                                             const float* __restrict__ b1,
                                             const unsigned short* __restrict__ w2tl,
                                             float* __restrict__ msg) {
  __shared__ float sHE[128*36];   // he[e][0..32], rows padded to 36
  __shared__ float sXS[128*36];   // xs[e][0..31]
  const int tid = threadIdx.x;
  const int be  = blockIdx.x*128;

  // --- stage he (edge MLP) ---
  {
    int el = tid >> 1, half = tid & 1;
    int e = be + el; e = min(e, N_EDGES-1);
    float eav[EDGE_F];
    const float4* ep = (const float4*)(ea + (size_t)e*EDGE_F);
    #pragma unroll
    for (int j = 0; j < 4; j++) {
      float4 v = ep[j];
      eav[4*j]=v.x; eav[4*j+1]=v.y; eav[4*j+2]=v.z; eav[4*j+3]=v.w;
    }
    #pragma unroll 4
    for (int k2 = 0; k2 < 16; k2++) {
      int k = half*16 + k2;
      float a = b1[k];
      #pragma unroll
      for (int j = 0; j < EDGE_F; j++) a = fmaf(eav[j], w1[j*HID+k], a);
      sHE[el*36 + k] = fmaxf(a, 0.f);
    }
    if (tid < 128) sHE[tid*36 + 32] = 1.0f;   // bias K-tile
  }
  // --- stage xs (gather source features) ---
  for (int i = tid; i < 128*8; i += 256) {
    int el = i >> 3, q = i & 7;
    int e = be + el; e = min(e, N_EDGES-1);
    int src = ei[e];
    src = min(max(src, 0), N_NODES-1);
    float4 v = ((const float4*)(hin + (size_t)src*HID))[q];
    ((float4*)(sXS + el*36))[q] = v;
  }
  __syncthreads();

  const int wv   = tid >> 6;          // wave 0..3
  const int lane = tid & 63;
  const int nn   = lane & 15;
  const int quad = lane >> 4;
  const int q8   = quad * 8;
  const int eb0  = wv*32;
  const int eb1  = wv*32 + 16;

  float4 x0a, x0b, x1a, x1b;
  {
    const float4* p0 = (const float4*)(sXS + (eb0+nn)*36 + q8);
    x0a = p0[0]; x0b = p0[1];
    const float4* p1 = (const float4*)(sXS + (eb1+nn)*36 + q8);
    x1a = p1[0]; x1b = p1[1];
  }

  f32x4 c00 = {0.f,0.f,0.f,0.f}, c01 = c00, c10 = c00, c11 = c00;
  const unsigned short* brow0 = w2tl + (unsigned)nn*KTOT + q8;
  const unsigned short* brow1 = brow0 + 16*KTOT;

  for (int kk = 0; kk < 33; kk++) {
    short8 b0 = *(const short8*)(brow0 + kk*32);
    short8 b1f = *(const short8*)(brow1 + kk*32);
    float hk0 = sHE[(eb0+nn)*36 + kk];
    float hk1 = sHE[(eb1+nn)*36 + kk];
    AFrag a0, a1;
    a0.u[0] = pkbf(hk0*x0a.x, hk0*x0a.y);
    a0.u[1] = pkbf(hk0*x0a.z, hk0*x0a.w);
    a0.u[2] = pkbf(hk0*x0b.x, hk0*x0b.y);
    a0.u[3] = pkbf(hk0*x0b.z, hk0*x0b.w);
    a1.u[0] = pkbf(hk1*x1a.x, hk1*x1a.y);
    a1.u[1] = pkbf(hk1*x1a.z, hk1*x1a.w);
    a1.u[2] = pkbf(hk1*x1b.x, hk1*x1b.y);
    a1.u[3] = pkbf(hk1*x1b.z, hk1*x1b.w);
    c00 = __builtin_amdgcn_mfma_f32_16x16x32_bf16(a0.v, b0,  c00, 0, 0, 0);
    c01 = __builtin_amdgcn_mfma_f32_16x16x32_bf16(a0.v, b1f, c01, 0, 0, 0);
    c10 = __builtin_amdgcn_mfma_f32_16x16x32_bf16(a1.v, b0,  c10, 0, 0, 0);
    c11 = __builtin_amdgcn_mfma_f32_16x16x32_bf16(a1.v, b1f, c11, 0, 0, 0);
  }

  #pragma unroll
  for (int r = 0; r < 4; r++) {
    int e0 = be + eb0 + quad*4 + r;
    if (e0 < N_EDGES) {
      msg[(size_t)e0*HID +      nn] = c00[r];
      msg[(size_t)e0*HID + 16 + nn] = c01[r];
    }
    int e1 = be + eb1 + quad*4 + r;
    if (e1 < N_EDGES) {
      msg[(size_t)e1*HID +      nn] = c10[r];
      msg[(size_t)e1*HID + 16 + nn] = c11[r];
    }
  }
}

// hout = relu( (sum_{e in CSR[n]} msg[e]) / max(deg,1) + hin @ root_w + root_b )
__global__ void k_gather(const float* __restrict__ msg,
                         const int* __restrict__ off, const int* __restrict__ elist,
                         const float* __restrict__ hin,
                         const float* __restrict__ rw,
                         const float* __restrict__ rb,
                         float* __restrict__ hout) {
  __shared__ float rws[HID*HID];
  __shared__ float rbs[HID];
  for (int i = threadIdx.x; i < HID*HID; i += 256) rws[i] = rw[i];
  if (threadIdx.x < HID) rbs[threadIdx.x] = rb[threadIdx.x];
  __syncthreads();
  int t = blockIdx.x*256 + threadIdx.x;
  if (t >= N_NODES*HID) return;
  int n = t >> 5, o = t & 31;
  int s0 = off[n], s1 = off[n+1];
  float sum = 0.f;
  for (int j = s0; j < s1; j++)
    sum += msg[(size_t)elist[j]*HID + o];
  float a = sum / fmaxf((float)(s1 - s0), 1.f) + rbs[o];
  const float4* hp = (const float4*)(hin + (size_t)n*HID);
  #pragma unroll
  for (int j = 0; j < HID/4; j++) {
    float4 v = hp[j];
    a = fmaf(v.x, rws[(4*j+0)*HID+o], a);
    a = fmaf(v.y, rws[(4*j+1)*HID+o], a);
    a = fmaf(v.z, rws[(4*j+2)*HID+o], a);
    a = fmaf(v.w, rws[(4*j+3)*HID+o], a);
  }
  hout[t] = fmaxf(a, 0.f);
}

// out = (relu((h@lo_w+lo_b)@d1_w+d1_b))@d2_w+d2_b   (no relu on z)
__global__ void k_decoder(const float* __restrict__ h,
                          const float* __restrict__ lo_w, const float* __restrict__ lo_b,
                          const float* __restrict__ d1_w, const float* __restrict__ d1_b,
                          const float* __restrict__ d2_w, const float* __restrict__ d2_b,
                          float* __restrict__ out) {
  __shared__ float lows[HID*LAT], lobs[LAT], d1s[LAT*HID], d1bs[HID], d2s[HID*NODE_F], d2bs[NODE_F];
  for (int i = threadIdx.x; i < HID*LAT; i += 256) lows[i] = lo_w[i];
  for (int i = threadIdx.x; i < LAT; i += 256) lobs[i] = lo_b[i];
  for (int i = threadIdx.x; i < LAT*HID; i += 256) d1s[i] = d1_w[i];
  for (int i = threadIdx.x; i < HID; i += 256) d1bs[i] = d1_b[i];
  for (int i = threadIdx.x; i < HID*NODE_F; i += 256) d2s[i] = d2_w[i];
  for (int i = threadIdx.x; i < NODE_F; i += 256) d2bs[i] = d2_b[i];
  __syncthreads();
  int n = blockIdx.x*256 + threadIdx.x;
  if (n >= N_NODES) return;
  float hr[HID];
  const float4* hp = (const float4*)(h + (size_t)n*HID);
  #pragma unroll
  for (int i = 0; i < HID/4; i++) { float4 v = hp[i]; hr[4*i]=v.x; hr[4*i+1]=v.y; hr[4*i+2]=v.z; hr[4*i+3]=v.w; }
  float z[LAT];
  #pragma unroll
  for (int o = 0; o < LAT; o++) {
    float a = lobs[o];
    #pragma unroll
    for (int j = 0; j < HID; j++) a = fmaf(hr[j], lows[j*LAT+o], a);
    z[o] = a;
  }
  float d[HID];
  #pragma unroll
  for (int o = 0; o < HID; o++) {
    float a = d1bs[o];
    #pragma unroll
    for (int j = 0; j < LAT; j++) a = fmaf(z[j], d1s[j*HID+o], a);
    d[o] = fmaxf(a, 0.f);
  }
  float* op = out + (size_t)n*NODE_F;
  #pragma unroll 8
  for (int o = 0; o < NODE_F; o++) {
    float a = d2bs[o];
    #pragma unroll
    for (int j = 0; j < HID; j++) a = fmaf(d[j], d2s[j*NODE_F+o], a);
    op[o] = a;
  }
}

extern "C" void kernel_launch(void* const* d_in, const int* in_sizes, int n_in,
                              void* d_out, int out_size, void* d_ws, size_t ws_size,
                              hipStream_t stream) {
  const float* x   = (const float*)d_in[0];
  const int*   ei  = (const int*)d_in[1];
  const float* ea  = (const float*)d_in[2];
  const float* liw = (const float*)d_in[3];
  const float* lib = (const float*)d_in[4];
  const float* ew1 = (const float*)d_in[5];
  const float* eb1 = (const float*)d_in[6];
  const float* ew2 = (const float*)d_in[7];
  const float* eb2 = (const float*)d_in[8];
  const float* rw  = (const float*)d_in[9];
  const float* rb  = (const float*)d_in[10];
  const float* low = (const float*)d_in[11];
  const float* lob = (const float*)d_in[12];
  const float* d1w = (const float*)d_in[13];
  const float* d1b = (const float*)d_in[14];
  const float* d2w = (const float*)d_in[15];
  const float* d2b = (const float*)d_in[16];
  float* out = (float*)d_out;

  float* h0   = (float*)d_ws;                          // 1.6M f
  float* h1   = h0  + (size_t)N_NODES*HID;             // 1.6M f
  float* msg  = h1  + (size_t)N_NODES*HID;             // 6.4M f
  int*  deg   = (int*)(msg + (size_t)N_EDGES*HID);     // 50k
  int*  off   = deg + N_NODES;                         // 50k+1 (alloc 50016)
  int*  cursor= off + N_NODES + 16;                    // 50k
  int*  elist = cursor + N_NODES;                      // 200k
  int*  bsum  = elist + N_EDGES;                       // 256
  unsigned short* w2t = (unsigned short*)(bsum + 256); // 3*32*1056 bf16

  // one-time prep
  k_prep_w2t<<<(3*HID*KTOT)/256, 256, 0, stream>>>(ew2, eb2, w2t);
  k_zero_int<<<(N_NODES + 255)/256, 256, 0, stream>>>(deg, N_NODES);
  k_hist<<<(N_EDGES + 255)/256, 256, 0, stream>>>(ei, deg);
  k_scan1<<<SCAN_BLOCKS, 256, 0, stream>>>(deg, off, bsum);
  k_scan2<<<1, 256, 0, stream>>>(bsum);
  k_scan3<<<(N_NODES + 255)/256, 256, 0, stream>>>(off, bsum, cursor);
  k_scatter<<<(N_EDGES + 255)/256, 256, 0, stream>>>(ei, off, cursor, elist);

  k_lin_in<<<(N_NODES*HID + 255)/256, 256, 0, stream>>>(x, liw, lib, h0);

  float* hin = h0; float* hout = h1;
  for (int i = 0; i < 3; i++) {
    k_msg<<<(N_EDGES + 127)/128, 256, 0, stream>>>(hin, ea, ei,
        ew1 + i*EDGE_F*HID, eb1 + i*HID,
        w2t + (size_t)i*HID*KTOT, msg);
    k_gather<<<(N_NODES*HID + 255)/256, 256, 0, stream>>>(msg, off, elist, hin,
        rw + i*HID*HID, rb + i*HID, hout);
    float* t = hin; hin = hout; hout = t;
  }

  k_decoder<<<(N_NODES + 255)/256, 256, 0, stream>>>(hin, low, lob, d1w, d1b, d2w, d2b, out);
}

// Round 8
// 356.470 us; speedup vs baseline: 6.0795x; 1.1460x over previous
//
#include <hip/hip_runtime.h>
#include <hip/hip_bf16.h>
#include <stdint.h>

#define N_NODES 50000
#define N_EDGES 200000
#define NODE_F 64
#define EDGE_F 16
#define HID 32
#define LAT 16
#define KTOT 1056   // 1024 + 32 (b2 folded in as 33rd K-tile)
#define SCAN_BLOCKS 196   // 196*256 = 50176 >= 50000

typedef __attribute__((ext_vector_type(8))) short short8;   // 8 bf16 = 4 VGPR
typedef __attribute__((ext_vector_type(4))) float f32x4;
typedef __attribute__((ext_vector_type(2))) float f32x2;

static __device__ __forceinline__ unsigned short bfbits(float f) {
  union { __hip_bfloat16 h; unsigned short s; } c; c.h = __float2bfloat16(f); return c.s;
}
// packed cvt: lo 16 bits = a.x, hi = a.y (v_cvt_pk_bf16_f32)
static __device__ __forceinline__ unsigned pk2(f32x2 v) {
  __hip_bfloat162 h = __float22bfloat162_rn(make_float2(v.x, v.y));
  unsigned u; __builtin_memcpy(&u, &h, 4); return u;
}
union AFrag { short8 v; unsigned u[4]; };

// --- CSR construction + weight transpose prep (once per call) ---
// also zeroes deg (merged to save a launch)
__global__ void k_prep(const float* __restrict__ ew2, const float* __restrict__ eb2,
                       unsigned short* __restrict__ w2t, int* __restrict__ deg) {
  int g = blockIdx.x*256 + threadIdx.x;          // 396*256 = 101376 exactly
  int l = g / (HID*KTOT);
  int r = g % (HID*KTOT);
  int o = r / KTOT;
  int kg = r % KTOT;
  int k = kg >> 5, h = kg & 31;
  float v = (k < 32) ? ew2[(size_t)l*32768 + k*1024 + h*32 + o]
                     : eb2[(size_t)l*1024 + h*32 + o];
  w2t[g] = bfbits(v);
  if (g < N_NODES) deg[g] = 0;
}

__global__ void k_hist(const int* __restrict__ ei, int* __restrict__ deg) {
  int t = blockIdx.x*256 + threadIdx.x;
  if (t >= N_EDGES) return;
  int d = ei[N_EDGES + t];
  d = min(max(d, 0), N_NODES-1);
  atomicAdd(&deg[d], 1);
}

__global__ __launch_bounds__(256) void k_scan1(const int* __restrict__ deg,
                                               int* __restrict__ off,
                                               int* __restrict__ bsum) {
  __shared__ int s[256];
  const int tid = threadIdx.x;
  const int t = blockIdx.x*256 + tid;
  int d = (t < N_NODES) ? deg[t] : 0;
  s[tid] = d; __syncthreads();
  int v = d;
  #pragma unroll
  for (int ofs = 1; ofs < 256; ofs <<= 1) {
    int w = (tid >= ofs) ? s[tid-ofs] : 0;
    __syncthreads();
    v += w; s[tid] = v;
    __syncthreads();
  }
  if (t < N_NODES) off[t] = v - d;
  if (tid == 255) bsum[blockIdx.x] = v;
}

__global__ __launch_bounds__(256) void k_scan2(int* __restrict__ bsum) {
  __shared__ int s[256];
  const int tid = threadIdx.x;
  int d = (tid < SCAN_BLOCKS) ? bsum[tid] : 0;
  s[tid] = d; __syncthreads();
  int v = d;
  #pragma unroll
  for (int ofs = 1; ofs < 256; ofs <<= 1) {
    int w = (tid >= ofs) ? s[tid-ofs] : 0;
    __syncthreads();
    v += w; s[tid] = v;
    __syncthreads();
  }
  if (tid < SCAN_BLOCKS) bsum[tid] = v - d;
}

__global__ void k_scan3(int* __restrict__ off, const int* __restrict__ bsum,
                        int* __restrict__ cursor) {
  int t = blockIdx.x*256 + threadIdx.x;
  if (t < N_NODES) {
    off[t] += bsum[t >> 8];
    cursor[t] = 0;
  }
  if (t == 0) off[N_NODES] = N_EDGES;
}

__global__ void k_scatter(const int* __restrict__ ei, const int* __restrict__ off,
                          int* __restrict__ cursor, int* __restrict__ elist) {
  int t = blockIdx.x*256 + threadIdx.x;
  if (t >= N_EDGES) return;
  int d = ei[N_EDGES + t];
  d = min(max(d, 0), N_NODES-1);
  int pos = atomicAdd(&cursor[d], 1);
  elist[off[d] + pos] = t;
}

// h = relu(x @ W + b)
__global__ void k_lin_in(const float* __restrict__ x,
                         const float* __restrict__ W,
                         const float* __restrict__ b,
                         float* __restrict__ h) {
  __shared__ float Ws[NODE_F*HID];
  __shared__ float bs[HID];
  for (int i = threadIdx.x; i < NODE_F*HID; i += 256) Ws[i] = W[i];
  if (threadIdx.x < HID) bs[threadIdx.x] = b[threadIdx.x];
  __syncthreads();
  int t = blockIdx.x*256 + threadIdx.x;
  if (t >= N_NODES*HID) return;
  int n = t >> 5, o = t & 31;
  const float4* xp = (const float4*)(x + (size_t)n*NODE_F);
  float acc = bs[o];
  #pragma unroll
  for (int j = 0; j < NODE_F/4; j++) {
    float4 v = xp[j];
    acc = fmaf(v.x, Ws[(4*j+0)*HID+o], acc);
    acc = fmaf(v.y, Ws[(4*j+1)*HID+o], acc);
    acc = fmaf(v.z, Ws[(4*j+2)*HID+o], acc);
    acc = fmaf(v.w, Ws[(4*j+3)*HID+o], acc);
  }
  h[t] = fmaxf(acc, 0.f);
}

// MFMA msg kernel: msg[E,32] = P[E,1056] @ W2R[1056,32], P[e, kk*32+h] = he[e,kk]*xs[e,h]
// 128 edges/block, 4 waves, 2 M-tiles/wave. he in LDS (stride 33, conflict-free);
// xs read directly from global (L2-hot); B prefetched 1 iter ahead; packed bf16 cvt.
__global__ __launch_bounds__(256) void k_msg(const float* __restrict__ hin,
                                             const float* __restrict__ ea,
                                             const int* __restrict__ ei,
                                             const float* __restrict__ w1,
                                             const float* __restrict__ b1,
                                             const unsigned short* __restrict__ w2tl,
                                             float* __restrict__ msg) {
  __shared__ float sHE[128*33];   // he[e][0..32], stride 33 -> 2-way max
  __shared__ int   sSRC[128];
  const int tid = threadIdx.x;
  const int be  = blockIdx.x*128;

  // --- stage he (edge MLP), 2 threads/edge ---
  {
    int el = tid >> 1, half = tid & 1;
    int e = min(be + el, N_EDGES-1);
    float eav[EDGE_F];
    const float4* ep = (const float4*)(ea + (size_t)e*EDGE_F);
    #pragma unroll
    for (int j = 0; j < 4; j++) {
      float4 v = ep[j];
      eav[4*j]=v.x; eav[4*j+1]=v.y; eav[4*j+2]=v.z; eav[4*j+3]=v.w;
    }
    #pragma unroll 4
    for (int k2 = 0; k2 < 16; k2++) {
      int k = half*16 + k2;
      float a = b1[k];
      #pragma unroll
      for (int j = 0; j < EDGE_F; j++) a = fmaf(eav[j], w1[j*HID+k], a);
      sHE[el*33 + k] = fmaxf(a, 0.f);
    }
  }
  if (tid < 128) {
    sHE[tid*33 + 32] = 1.0f;   // bias K-tile
    int e = min(be + tid, N_EDGES-1);
    sSRC[tid] = min(max(ei[e], 0), N_NODES-1);
  }
  __syncthreads();

  const int wv   = tid >> 6;          // wave 0..3
  const int lane = tid & 63;
  const int nn   = lane & 15;
  const int quad = lane >> 4;
  const int eb0  = wv*32;
  const int eb1  = wv*32 + 16;

  // xs straight from global
  f32x2 xA[4], xB[4];
  {
    int s0i = sSRC[eb0+nn];
    int s1i = sSRC[eb1+nn];
    const float4* p0 = (const float4*)(hin + (size_t)s0i*HID);
    const float4* p1 = (const float4*)(hin + (size_t)s1i*HID);
    float4 a0 = p0[quad*2], a1 = p0[quad*2+1];
    float4 b0 = p1[quad*2], b1v = p1[quad*2+1];
    xA[0] = f32x2{a0.x, a0.y}; xA[1] = f32x2{a0.z, a0.w};
    xA[2] = f32x2{a1.x, a1.y}; xA[3] = f32x2{a1.z, a1.w};
    xB[0] = f32x2{b0.x, b0.y}; xB[1] = f32x2{b0.z, b0.w};
    xB[2] = f32x2{b1v.x, b1v.y}; xB[3] = f32x2{b1v.z, b1v.w};
  }

  f32x4 c00 = {0.f,0.f,0.f,0.f}, c01 = c00, c10 = c00, c11 = c00;
  const unsigned short* bp0 = w2tl + (unsigned)nn*KTOT + quad*8;
  const unsigned short* bp1 = bp0 + 16*KTOT;

  short8 cb0 = *(const short8*)(bp0);
  short8 cb1 = *(const short8*)(bp1);
  const float* heRow0 = sHE + (eb0+nn)*33;
  const float* heRow1 = sHE + (eb1+nn)*33;

  for (int kk = 0; kk < 33; kk++) {
    short8 nb0, nb1;
    if (kk < 32) {
      nb0 = *(const short8*)(bp0 + (kk+1)*32);
      nb1 = *(const short8*)(bp1 + (kk+1)*32);
    }
    float hk0 = heRow0[kk];
    float hk1 = heRow1[kk];
    AFrag a0, a1;
    #pragma unroll
    for (int i = 0; i < 4; i++) {
      a0.u[i] = pk2(xA[i]*hk0);
      a1.u[i] = pk2(xB[i]*hk1);
    }
    c00 = __builtin_amdgcn_mfma_f32_16x16x32_bf16(a0.v, cb0, c00, 0, 0, 0);
    c01 = __builtin_amdgcn_mfma_f32_16x16x32_bf16(a0.v, cb1, c01, 0, 0, 0);
    c10 = __builtin_amdgcn_mfma_f32_16x16x32_bf16(a1.v, cb0, c10, 0, 0, 0);
    c11 = __builtin_amdgcn_mfma_f32_16x16x32_bf16(a1.v, cb1, c11, 0, 0, 0);
    cb0 = nb0; cb1 = nb1;
  }

  #pragma unroll
  for (int r = 0; r < 4; r++) {
    int e0 = be + eb0 + quad*4 + r;
    if (e0 < N_EDGES) {
      msg[(size_t)e0*HID +      nn] = c00[r];
      msg[(size_t)e0*HID + 16 + nn] = c01[r];
    }
    int e1 = be + eb1 + quad*4 + r;
    if (e1 < N_EDGES) {
      msg[(size_t)e1*HID +      nn] = c10[r];
      msg[(size_t)e1*HID + 16 + nn] = c11[r];
    }
  }
}

// hout = relu( (sum_{e in CSR[n]} msg[e]) / max(deg,1) + hin @ root_w + root_b )
// float4 per thread: thread = (n, oc), oc covers outputs oc*4..oc*4+3
__global__ void k_gather(const float* __restrict__ msg,
                         const int* __restrict__ off, const int* __restrict__ elist,
                         const float* __restrict__ hin,
                         const float* __restrict__ rw,
                         const float* __restrict__ rb,
                         float* __restrict__ hout) {
  __shared__ float rws[HID*HID];
  __shared__ float rbs[HID];
  for (int i = threadIdx.x; i < HID*HID; i += 256) rws[i] = rw[i];
  if (threadIdx.x < HID) rbs[threadIdx.x] = rb[threadIdx.x];
  __syncthreads();
  int t = blockIdx.x*256 + threadIdx.x;
  if (t >= N_NODES*8) return;
  int n = t >> 3, oc = t & 7;
  int s0 = off[n], s1 = off[n+1];
  float a0 = 0.f, a1 = 0.f, a2 = 0.f, a3 = 0.f;
  for (int j = s0; j < s1; j++) {
    int e = elist[j];
    float4 v = ((const float4*)(msg + (size_t)e*HID))[oc];
    a0 += v.x; a1 += v.y; a2 += v.z; a3 += v.w;
  }
  float inv = 1.f / fmaxf((float)(s1 - s0), 1.f);
  a0 = fmaf(a0, inv, rbs[oc*4+0]);
  a1 = fmaf(a1, inv, rbs[oc*4+1]);
  a2 = fmaf(a2, inv, rbs[oc*4+2]);
  a3 = fmaf(a3, inv, rbs[oc*4+3]);
  const float4* hp = (const float4*)(hin + (size_t)n*HID);
  #pragma unroll
  for (int jq = 0; jq < 8; jq++) {
    float4 hv = hp[jq];
    #pragma unroll
    for (int c = 0; c < 4; c++) {
      int j = jq*4 + c;
      float h = (c==0)?hv.x:(c==1)?hv.y:(c==2)?hv.z:hv.w;
      const float4* rp = (const float4*)(rws + j*HID + oc*4);
      float4 r = rp[0];
      a0 = fmaf(h, r.x, a0);
      a1 = fmaf(h, r.y, a1);
      a2 = fmaf(h, r.z, a2);
      a3 = fmaf(h, r.w, a3);
    }
  }
  float4 res = make_float4(fmaxf(a0,0.f), fmaxf(a1,0.f), fmaxf(a2,0.f), fmaxf(a3,0.f));
  ((float4*)(hout + (size_t)n*HID))[oc] = res;
}

// out = (relu((h@lo_w+lo_b)@d1_w+d1_b))@d2_w+d2_b   (no relu on z)
__global__ void k_decoder(const float* __restrict__ h,
                          const float* __restrict__ lo_w, const float* __restrict__ lo_b,
                          const float* __restrict__ d1_w, const float* __restrict__ d1_b,
                          const float* __restrict__ d2_w, const float* __restrict__ d2_b,
                          float* __restrict__ out) {
  __shared__ float lows[HID*LAT], lobs[LAT], d1s[LAT*HID], d1bs[HID], d2s[HID*NODE_F], d2bs[NODE_F];
  for (int i = threadIdx.x; i < HID*LAT; i += 256) lows[i] = lo_w[i];
  for (int i = threadIdx.x; i < LAT; i += 256) lobs[i] = lo_b[i];
  for (int i = threadIdx.x; i < LAT*HID; i += 256) d1s[i] = d1_w[i];
  for (int i = threadIdx.x; i < HID; i += 256) d1bs[i] = d1_b[i];
  for (int i = threadIdx.x; i < HID*NODE_F; i += 256) d2s[i] = d2_w[i];
  for (int i = threadIdx.x; i < NODE_F; i += 256) d2bs[i] = d2_b[i];
  __syncthreads();
  int n = blockIdx.x*256 + threadIdx.x;
  if (n >= N_NODES) return;
  float hr[HID];
  const float4* hp = (const float4*)(h + (size_t)n*HID);
  #pragma unroll
  for (int i = 0; i < HID/4; i++) { float4 v = hp[i]; hr[4*i]=v.x; hr[4*i+1]=v.y; hr[4*i+2]=v.z; hr[4*i+3]=v.w; }
  float z[LAT];
  #pragma unroll
  for (int o = 0; o < LAT; o++) {
    float a = lobs[o];
    #pragma unroll
    for (int j = 0; j < HID; j++) a = fmaf(hr[j], lows[j*LAT+o], a);
    z[o] = a;
  }
  float d[HID];
  #pragma unroll
  for (int o = 0; o < HID; o++) {
    float a = d1bs[o];
    #pragma unroll
    for (int j = 0; j < LAT; j++) a = fmaf(z[j], d1s[j*HID+o], a);
    d[o] = fmaxf(a, 0.f);
  }
  float* op = out + (size_t)n*NODE_F;
  #pragma unroll 8
  for (int o = 0; o < NODE_F; o++) {
    float a = d2bs[o];
    #pragma unroll
    for (int j = 0; j < HID; j++) a = fmaf(d[j], d2s[j*NODE_F+o], a);
    op[o] = a;
  }
}

extern "C" void kernel_launch(void* const* d_in, const int* in_sizes, int n_in,
                              void* d_out, int out_size, void* d_ws, size_t ws_size,
                              hipStream_t stream) {
  const float* x   = (const float*)d_in[0];
  const int*   ei  = (const int*)d_in[1];
  const float* ea  = (const float*)d_in[2];
  const float* liw = (const float*)d_in[3];
  const float* lib = (const float*)d_in[4];
  const float* ew1 = (const float*)d_in[5];
  const float* eb1 = (const float*)d_in[6];
  const float* ew2 = (const float*)d_in[7];
  const float* eb2 = (const float*)d_in[8];
  const float* rw  = (const float*)d_in[9];
  const float* rb  = (const float*)d_in[10];
  const float* low = (const float*)d_in[11];
  const float* lob = (const float*)d_in[12];
  const float* d1w = (const float*)d_in[13];
  const float* d1b = (const float*)d_in[14];
  const float* d2w = (const float*)d_in[15];
  const float* d2b = (const float*)d_in[16];
  float* out = (float*)d_out;

  float* h0   = (float*)d_ws;                          // 1.6M f
  float* h1   = h0  + (size_t)N_NODES*HID;             // 1.6M f
  float* msg  = h1  + (size_t)N_NODES*HID;             // 6.4M f
  int*  deg   = (int*)(msg + (size_t)N_EDGES*HID);     // 50k
  int*  off   = deg + N_NODES;                         // 50k+1 (alloc 50016)
  int*  cursor= off + N_NODES + 16;                    // 50k
  int*  elist = cursor + N_NODES;                      // 200k
  int*  bsum  = elist + N_EDGES;                       // 256
  unsigned short* w2t = (unsigned short*)(bsum + 256); // 3*32*1056 bf16

  k_prep<<<(3*HID*KTOT)/256, 256, 0, stream>>>(ew2, eb2, w2t, deg);
  k_hist<<<(N_EDGES + 255)/256, 256, 0, stream>>>(ei, deg);
  k_scan1<<<SCAN_BLOCKS, 256, 0, stream>>>(deg, off, bsum);
  k_scan2<<<1, 256, 0, stream>>>(bsum);
  k_scan3<<<(N_NODES + 255)/256, 256, 0, stream>>>(off, bsum, cursor);
  k_scatter<<<(N_EDGES + 255)/256, 256, 0, stream>>>(ei, off, cursor, elist);

  k_lin_in<<<(N_NODES*HID + 255)/256, 256, 0, stream>>>(x, liw, lib, h0);

  float* hin = h0; float* hout = h1;
  for (int i = 0; i < 3; i++) {
    k_msg<<<(N_EDGES + 127)/128, 256, 0, stream>>>(hin, ea, ei,
        ew1 + i*EDGE_F*HID, eb1 + i*HID,
        w2t + (size_t)i*HID*KTOT, msg);
    k_gather<<<(N_NODES*8 + 255)/256, 256, 0, stream>>>(msg, off, elist, hin,
        rw + i*HID*HID, rb + i*HID, hout);
    float* t = hin; hin = hout; hout = t;
  }

  k_decoder<<<(N_NODES + 255)/256, 256, 0, stream>>>(hin, low, lob, d1w, d1b, d2w, d2b, out);
}

// Round 9
// 355.837 us; speedup vs baseline: 6.0903x; 1.0018x over previous
//
#include <hip/hip_runtime.h>
#include <hip/hip_bf16.h>
#include <stdint.h>

#define N_NODES 50000
#define N_EDGES 200000
#define NODE_F 64
#define EDGE_F 16
#define HID 32
#define LAT 16
#define KTOT 1056   // 1024 + 32 (b2 folded in as 33rd K-tile)
#define SCAN_BLOCKS 196   // 196*256 = 50176 >= 50000

typedef __attribute__((ext_vector_type(8))) short short8;   // 8 bf16 = 4 VGPR
typedef __attribute__((ext_vector_type(4))) float f32x4;
typedef __attribute__((ext_vector_type(2))) float f32x2;

static __device__ __forceinline__ unsigned short bfbits(float f) {
  union { __hip_bfloat16 h; unsigned short s; } c; c.h = __float2bfloat16(f); return c.s;
}
// packed cvt: lo 16 bits = a.x, hi = a.y (v_cvt_pk_bf16_f32)
static __device__ __forceinline__ unsigned pk2(f32x2 v) {
  __hip_bfloat162 h = __float22bfloat162_rn(make_float2(v.x, v.y));
  unsigned u; __builtin_memcpy(&u, &h, 4); return u;
}
union AFrag { short8 v; unsigned u[4]; };

// --- CSR construction + weight transpose prep (once per call) ---
__global__ void k_prep(const float* __restrict__ ew2, const float* __restrict__ eb2,
                       unsigned short* __restrict__ w2t, int* __restrict__ deg) {
  int g = blockIdx.x*256 + threadIdx.x;          // 396*256 = 101376 exactly
  int l = g / (HID*KTOT);
  int r = g % (HID*KTOT);
  int o = r / KTOT;
  int kg = r % KTOT;
  int k = kg >> 5, h = kg & 31;
  float v = (k < 32) ? ew2[(size_t)l*32768 + k*1024 + h*32 + o]
                     : eb2[(size_t)l*1024 + h*32 + o];
  w2t[g] = bfbits(v);
  if (g < N_NODES) deg[g] = 0;
}

__global__ void k_hist(const int* __restrict__ ei, int* __restrict__ deg) {
  int t = blockIdx.x*256 + threadIdx.x;
  if (t >= N_EDGES) return;
  int d = ei[N_EDGES + t];
  d = min(max(d, 0), N_NODES-1);
  atomicAdd(&deg[d], 1);
}

__global__ __launch_bounds__(256) void k_scan1(const int* __restrict__ deg,
                                               int* __restrict__ off,
                                               int* __restrict__ bsum) {
  __shared__ int s[256];
  const int tid = threadIdx.x;
  const int t = blockIdx.x*256 + tid;
  int d = (t < N_NODES) ? deg[t] : 0;
  s[tid] = d; __syncthreads();
  int v = d;
  #pragma unroll
  for (int ofs = 1; ofs < 256; ofs <<= 1) {
    int w = (tid >= ofs) ? s[tid-ofs] : 0;
    __syncthreads();
    v += w; s[tid] = v;
    __syncthreads();
  }
  if (t < N_NODES) off[t] = v - d;
  if (tid == 255) bsum[blockIdx.x] = v;
}

__global__ __launch_bounds__(256) void k_scan2(int* __restrict__ bsum) {
  __shared__ int s[256];
  const int tid = threadIdx.x;
  int d = (tid < SCAN_BLOCKS) ? bsum[tid] : 0;
  s[tid] = d; __syncthreads();
  int v = d;
  #pragma unroll
  for (int ofs = 1; ofs < 256; ofs <<= 1) {
    int w = (tid >= ofs) ? s[tid-ofs] : 0;
    __syncthreads();
    v += w; s[tid] = v;
    __syncthreads();
  }
  if (tid < SCAN_BLOCKS) bsum[tid] = v - d;
}

__global__ void k_scan3(int* __restrict__ off, const int* __restrict__ bsum,
                        int* __restrict__ cursor) {
  int t = blockIdx.x*256 + threadIdx.x;
  if (t < N_NODES) {
    off[t] += bsum[t >> 8];
    cursor[t] = 0;
  }
  if (t == 0) off[N_NODES] = N_EDGES;
}

__global__ void k_scatter(const int* __restrict__ ei, const int* __restrict__ off,
                          int* __restrict__ cursor, int* __restrict__ elist) {
  int t = blockIdx.x*256 + threadIdx.x;
  if (t >= N_EDGES) return;
  int d = ei[N_EDGES + t];
  d = min(max(d, 0), N_NODES-1);
  int pos = atomicAdd(&cursor[d], 1);
  elist[off[d] + pos] = t;
}

// h = relu(x @ W + b)
__global__ void k_lin_in(const float* __restrict__ x,
                         const float* __restrict__ W,
                         const float* __restrict__ b,
                         float* __restrict__ h) {
  __shared__ float Ws[NODE_F*HID];
  __shared__ float bs[HID];
  for (int i = threadIdx.x; i < NODE_F*HID; i += 256) Ws[i] = W[i];
  if (threadIdx.x < HID) bs[threadIdx.x] = b[threadIdx.x];
  __syncthreads();
  int t = blockIdx.x*256 + threadIdx.x;
  if (t >= N_NODES*HID) return;
  int n = t >> 5, o = t & 31;
  const float4* xp = (const float4*)(x + (size_t)n*NODE_F);
  float acc = bs[o];
  #pragma unroll
  for (int j = 0; j < NODE_F/4; j++) {
    float4 v = xp[j];
    acc = fmaf(v.x, Ws[(4*j+0)*HID+o], acc);
    acc = fmaf(v.y, Ws[(4*j+1)*HID+o], acc);
    acc = fmaf(v.z, Ws[(4*j+2)*HID+o], acc);
    acc = fmaf(v.w, Ws[(4*j+3)*HID+o], acc);
  }
  h[t] = fmaxf(acc, 0.f);
}

// MFMA msg kernel: msg[E,32] = P[E,1056] @ W2R[1056,32], P[e, kk*32+h] = he[e,kk]*xs[e,h]
// 128 edges/block, 4 waves, 2 M-tiles/wave; depth-3 register pipeline on B (global)
// and he (LDS) so loads stay ~2 full iterations ahead of their MFMA use.
__global__ __launch_bounds__(256) void k_msg(const float* __restrict__ hin,
                                             const float* __restrict__ ea,
                                             const int* __restrict__ ei,
                                             const float* __restrict__ w1,
                                             const float* __restrict__ b1,
                                             const unsigned short* __restrict__ w2tl,
                                             float* __restrict__ msg) {
  __shared__ float sHE[128*33];   // he[e][0..32], stride 33 -> 2-way max
  __shared__ int   sSRC[128];
  const int tid = threadIdx.x;
  const int be  = blockIdx.x*128;

  // --- stage he (edge MLP), 2 threads/edge ---
  {
    int el = tid >> 1, half = tid & 1;
    int e = min(be + el, N_EDGES-1);
    float eav[EDGE_F];
    const float4* ep = (const float4*)(ea + (size_t)e*EDGE_F);
    #pragma unroll
    for (int j = 0; j < 4; j++) {
      float4 v = ep[j];
      eav[4*j]=v.x; eav[4*j+1]=v.y; eav[4*j+2]=v.z; eav[4*j+3]=v.w;
    }
    #pragma unroll 4
    for (int k2 = 0; k2 < 16; k2++) {
      int k = half*16 + k2;
      float a = b1[k];
      #pragma unroll
      for (int j = 0; j < EDGE_F; j++) a = fmaf(eav[j], w1[j*HID+k], a);
      sHE[el*33 + k] = fmaxf(a, 0.f);
    }
  }
  if (tid < 128) {
    sHE[tid*33 + 32] = 1.0f;   // bias K-tile
    int e = min(be + tid, N_EDGES-1);
    sSRC[tid] = min(max(ei[e], 0), N_NODES-1);
  }
  __syncthreads();

  const int wv   = tid >> 6;          // wave 0..3
  const int lane = tid & 63;
  const int nn   = lane & 15;
  const int quad = lane >> 4;
  const int eb0  = wv*32;
  const int eb1  = wv*32 + 16;

  // xs straight from global (L2-hot)
  f32x2 xA[4], xB[4];
  {
    int s0i = sSRC[eb0+nn];
    int s1i = sSRC[eb1+nn];
    const float4* p0 = (const float4*)(hin + (size_t)s0i*HID);
    const float4* p1 = (const float4*)(hin + (size_t)s1i*HID);
    float4 a0 = p0[quad*2], a1 = p0[quad*2+1];
    float4 b0 = p1[quad*2], b1v = p1[quad*2+1];
    xA[0] = f32x2{a0.x, a0.y}; xA[1] = f32x2{a0.z, a0.w};
    xA[2] = f32x2{a1.x, a1.y}; xA[3] = f32x2{a1.z, a1.w};
    xB[0] = f32x2{b0.x, b0.y}; xB[1] = f32x2{b0.z, b0.w};
    xB[2] = f32x2{b1v.x, b1v.y}; xB[3] = f32x2{b1v.z, b1v.w};
  }

  f32x4 c00 = {0.f,0.f,0.f,0.f}, c01 = c00, c10 = c00, c11 = c00;
  const unsigned short* bp0 = w2tl + (unsigned)nn*KTOT + quad*8;
  const unsigned short* bp1 = bp0 + 16*KTOT;
  const float* heRow0 = sHE + (eb0+nn)*33;
  const float* heRow1 = sHE + (eb1+nn)*33;

  // depth-3 pipeline slots
  short8 sb0[3], sb1[3];
  float  sh0[3], sh1[3];
  #pragma unroll
  for (int j = 0; j < 3; j++) {
    sb0[j] = *(const short8*)(bp0 + j*32);
    sb1[j] = *(const short8*)(bp1 + j*32);
    sh0[j] = heRow0[j];
    sh1[j] = heRow1[j];
  }

  #pragma unroll 1
  for (int base = 0; base < 30; base += 3) {
    #pragma unroll
    for (int j = 0; j < 3; j++) {
      const int kk = base + j;
      float hk0 = sh0[j], hk1 = sh1[j];
      AFrag a0, a1;
      #pragma unroll
      for (int i = 0; i < 4; i++) {
        a0.u[i] = pk2(xA[i]*hk0);
        a1.u[i] = pk2(xB[i]*hk1);
      }
      short8 cb0 = sb0[j], cb1 = sb1[j];
      c00 = __builtin_amdgcn_mfma_f32_16x16x32_bf16(a0.v, cb0, c00, 0, 0, 0);
      c01 = __builtin_amdgcn_mfma_f32_16x16x32_bf16(a0.v, cb1, c01, 0, 0, 0);
      c10 = __builtin_amdgcn_mfma_f32_16x16x32_bf16(a1.v, cb0, c10, 0, 0, 0);
      c11 = __builtin_amdgcn_mfma_f32_16x16x32_bf16(a1.v, cb1, c11, 0, 0, 0);
      // refill slot j with kk+3 (max 32)
      sb0[j] = *(const short8*)(bp0 + (kk+3)*32);
      sb1[j] = *(const short8*)(bp1 + (kk+3)*32);
      sh0[j] = heRow0[kk+3];
      sh1[j] = heRow1[kk+3];
    }
  }
  // tail: kk = 30,31,32 from slots
  #pragma unroll
  for (int j = 0; j < 3; j++) {
    float hk0 = sh0[j], hk1 = sh1[j];
    AFrag a0, a1;
    #pragma unroll
    for (int i = 0; i < 4; i++) {
      a0.u[i] = pk2(xA[i]*hk0);
      a1.u[i] = pk2(xB[i]*hk1);
    }
    c00 = __builtin_amdgcn_mfma_f32_16x16x32_bf16(a0.v, sb0[j], c00, 0, 0, 0);
    c01 = __builtin_amdgcn_mfma_f32_16x16x32_bf16(a0.v, sb1[j], c01, 0, 0, 0);
    c10 = __builtin_amdgcn_mfma_f32_16x16x32_bf16(a1.v, sb0[j], c10, 0, 0, 0);
    c11 = __builtin_amdgcn_mfma_f32_16x16x32_bf16(a1.v, sb1[j], c11, 0, 0, 0);
  }

  #pragma unroll
  for (int r = 0; r < 4; r++) {
    int e0 = be + eb0 + quad*4 + r;
    if (e0 < N_EDGES) {
      msg[(size_t)e0*HID +      nn] = c00[r];
      msg[(size_t)e0*HID + 16 + nn] = c01[r];
    }
    int e1 = be + eb1 + quad*4 + r;
    if (e1 < N_EDGES) {
      msg[(size_t)e1*HID +      nn] = c10[r];
      msg[(size_t)e1*HID + 16 + nn] = c11[r];
    }
  }
}

// hout = relu( (sum_{e in CSR[n]} msg[e]) / max(deg,1) + hin @ root_w + root_b )
__global__ void k_gather(const float* __restrict__ msg,
                         const int* __restrict__ off, const int* __restrict__ elist,
                         const float* __restrict__ hin,
                         const float* __restrict__ rw,
                         const float* __restrict__ rb,
                         float* __restrict__ hout) {
  __shared__ float rws[HID*HID];
  __shared__ float rbs[HID];
  for (int i = threadIdx.x; i < HID*HID; i += 256) rws[i] = rw[i];
  if (threadIdx.x < HID) rbs[threadIdx.x] = rb[threadIdx.x];
  __syncthreads();
  int t = blockIdx.x*256 + threadIdx.x;
  if (t >= N_NODES*8) return;
  int n = t >> 3, oc = t & 7;
  int s0 = off[n], s1 = off[n+1];
  float a0 = 0.f, a1 = 0.f, a2 = 0.f, a3 = 0.f;
  for (int j = s0; j < s1; j++) {
    int e = elist[j];
    float4 v = ((const float4*)(msg + (size_t)e*HID))[oc];
    a0 += v.x; a1 += v.y; a2 += v.z; a3 += v.w;
  }
  float inv = 1.f / fmaxf((float)(s1 - s0), 1.f);
  a0 = fmaf(a0, inv, rbs[oc*4+0]);
  a1 = fmaf(a1, inv, rbs[oc*4+1]);
  a2 = fmaf(a2, inv, rbs[oc*4+2]);
  a3 = fmaf(a3, inv, rbs[oc*4+3]);
  const float4* hp = (const float4*)(hin + (size_t)n*HID);
  #pragma unroll
  for (int jq = 0; jq < 8; jq++) {
    float4 hv = hp[jq];
    #pragma unroll
    for (int c = 0; c < 4; c++) {
      int j = jq*4 + c;
      float h = (c==0)?hv.x:(c==1)?hv.y:(c==2)?hv.z:hv.w;
      const float4* rp = (const float4*)(rws + j*HID + oc*4);
      float4 r = rp[0];
      a0 = fmaf(h, r.x, a0);
      a1 = fmaf(h, r.y, a1);
      a2 = fmaf(h, r.z, a2);
      a3 = fmaf(h, r.w, a3);
    }
  }
  float4 res = make_float4(fmaxf(a0,0.f), fmaxf(a1,0.f), fmaxf(a2,0.f), fmaxf(a3,0.f));
  ((float4*)(hout + (size_t)n*HID))[oc] = res;
}

// out = (relu((h@lo_w+lo_b)@d1_w+d1_b))@d2_w+d2_b   (no relu on z)
__global__ void k_decoder(const float* __restrict__ h,
                          const float* __restrict__ lo_w, const float* __restrict__ lo_b,
                          const float* __restrict__ d1_w, const float* __restrict__ d1_b,
                          const float* __restrict__ d2_w, const float* __restrict__ d2_b,
                          float* __restrict__ out) {
  __shared__ float lows[HID*LAT], lobs[LAT], d1s[LAT*HID], d1bs[HID], d2s[HID*NODE_F], d2bs[NODE_F];
  for (int i = threadIdx.x; i < HID*LAT; i += 256) lows[i] = lo_w[i];
  for (int i = threadIdx.x; i < LAT; i += 256) lobs[i] = lo_b[i];
  for (int i = threadIdx.x; i < LAT*HID; i += 256) d1s[i] = d1_w[i];
  for (int i = threadIdx.x; i < HID; i += 256) d1bs[i] = d1_b[i];
  for (int i = threadIdx.x; i < HID*NODE_F; i += 256) d2s[i] = d2_w[i];
  for (int i = threadIdx.x; i < NODE_F; i += 256) d2bs[i] = d2_b[i];
  __syncthreads();
  int n = blockIdx.x*256 + threadIdx.x;
  if (n >= N_NODES) return;
  float hr[HID];
  const float4* hp = (const float4*)(h + (size_t)n*HID);
  #pragma unroll
  for (int i = 0; i < HID/4; i++) { float4 v = hp[i]; hr[4*i]=v.x; hr[4*i+1]=v.y; hr[4*i+2]=v.z; hr[4*i+3]=v.w; }
  float z[LAT];
  #pragma unroll
  for (int o = 0; o < LAT; o++) {
    float a = lobs[o];
    #pragma unroll
    for (int j = 0; j < HID; j++) a = fmaf(hr[j], lows[j*LAT+o], a);
    z[o] = a;
  }
  float d[HID];
  #pragma unroll
  for (int o = 0; o < HID; o++) {
    float a = d1bs[o];
    #pragma unroll
    for (int j = 0; j < LAT; j++) a = fmaf(z[j], d1s[j*HID+o], a);
    d[o] = fmaxf(a, 0.f);
  }
  float* op = out + (size_t)n*NODE_F;
  #pragma unroll 8
  for (int o = 0; o < NODE_F; o++) {
    float a = d2bs[o];
    #pragma unroll
    for (int j = 0; j < HID; j++) a = fmaf(d[j], d2s[j*NODE_F+o], a);
    op[o] = a;
  }
}

extern "C" void kernel_launch(void* const* d_in, const int* in_sizes, int n_in,
                              void* d_out, int out_size, void* d_ws, size_t ws_size,
                              hipStream_t stream) {
  const float* x   = (const float*)d_in[0];
  const int*   ei  = (const int*)d_in[1];
  const float* ea  = (const float*)d_in[2];
  const float* liw = (const float*)d_in[3];
  const float* lib = (const float*)d_in[4];
  const float* ew1 = (const float*)d_in[5];
  const float* eb1 = (const float*)d_in[6];
  const float* ew2 = (const float*)d_in[7];
  const float* eb2 = (const float*)d_in[8];
  const float* rw  = (const float*)d_in[9];
  const float* rb  = (const float*)d_in[10];
  const float* low = (const float*)d_in[11];
  const float* lob = (const float*)d_in[12];
  const float* d1w = (const float*)d_in[13];
  const float* d1b = (const float*)d_in[14];
  const float* d2w = (const float*)d_in[15];
  const float* d2b = (const float*)d_in[16];
  float* out = (float*)d_out;

  float* h0   = (float*)d_ws;                          // 1.6M f
  float* h1   = h0  + (size_t)N_NODES*HID;             // 1.6M f
  float* msg  = h1  + (size_t)N_NODES*HID;             // 6.4M f
  int*  deg   = (int*)(msg + (size_t)N_EDGES*HID);     // 50k
  int*  off   = deg + N_NODES;                         // 50k+1 (alloc 50016)
  int*  cursor= off + N_NODES + 16;                    // 50k
  int*  elist = cursor + N_NODES;                      // 200k
  int*  bsum  = elist + N_EDGES;                       // 256
  unsigned short* w2t = (unsigned short*)(bsum + 256); // 3*32*1056 bf16

  k_prep<<<(3*HID*KTOT)/256, 256, 0, stream>>>(ew2, eb2, w2t, deg);
  k_hist<<<(N_EDGES + 255)/256, 256, 0, stream>>>(ei, deg);
  k_scan1<<<SCAN_BLOCKS, 256, 0, stream>>>(deg, off, bsum);
  k_scan2<<<1, 256, 0, stream>>>(bsum);
  k_scan3<<<(N_NODES + 255)/256, 256, 0, stream>>>(off, bsum, cursor);
  k_scatter<<<(N_EDGES + 255)/256, 256, 0, stream>>>(ei, off, cursor, elist);

  k_lin_in<<<(N_NODES*HID + 255)/256, 256, 0, stream>>>(x, liw, lib, h0);

  float* hin = h0; float* hout = h1;
  for (int i = 0; i < 3; i++) {
    k_msg<<<(N_EDGES + 127)/128, 256, 0, stream>>>(hin, ea, ei,
        ew1 + i*EDGE_F*HID, eb1 + i*HID,
        w2t + (size_t)i*HID*KTOT, msg);
    k_gather<<<(N_NODES*8 + 255)/256, 256, 0, stream>>>(msg, off, elist, hin,
        rw + i*HID*HID, rb + i*HID, hout);
    float* t = hin; hin = hout; hout = t;
  }

  k_decoder<<<(N_NODES + 255)/256, 256, 0, stream>>>(hin, low, lob, d1w, d1b, d2w, d2b, out);
}

// Round 10
// 316.848 us; speedup vs baseline: 6.8397x; 1.1231x over previous
//
#include <hip/hip_runtime.h>
#include <hip/hip_bf16.h>
#include <stdint.h>

#define N_NODES 50000
#define N_EDGES 200000
#define NODE_F 64
#define EDGE_F 16
#define HID 32
#define LAT 16
#define KTOT 1056   // 1024 + 32 (b2 folded in as 33rd K-tile)
#define SCAN_BLOCKS 196   // 196*256 = 50176 >= 50000

typedef __attribute__((ext_vector_type(8))) short short8;   // 8 bf16 = 4 VGPR
typedef __attribute__((ext_vector_type(4))) float f32x4;
typedef __attribute__((ext_vector_type(2))) float f32x2;

static __device__ __forceinline__ unsigned short bfbits(float f) {
  union { __hip_bfloat16 h; unsigned short s; } c; c.h = __float2bfloat16(f); return c.s;
}
// packed cvt: lo 16 bits = a.x, hi = a.y (v_cvt_pk_bf16_f32)
static __device__ __forceinline__ unsigned pk2(f32x2 v) {
  __hip_bfloat162 h = __float22bfloat162_rn(make_float2(v.x, v.y));
  unsigned u; __builtin_memcpy(&u, &h, 4); return u;
}
union AFrag { short8 v; unsigned u[4]; };

// --- prep: w2 transpose to bf16 B-layout, w1 packed into per-lane B-fragments,
//     deg zeroing (all fused, once per call) ---
__global__ void k_prep(const float* __restrict__ ew2, const float* __restrict__ eb2,
                       const float* __restrict__ ew1,
                       unsigned short* __restrict__ w2t,
                       unsigned short* __restrict__ w1p,
                       int* __restrict__ deg) {
  int g = blockIdx.x*256 + threadIdx.x;          // 396*256 = 101376 exactly
  int l = g / (HID*KTOT);
  int r = g % (HID*KTOT);
  int o = r / KTOT;
  int kg = r % KTOT;
  int k = kg >> 5, h = kg & 31;
  float v = (k < 32) ? ew2[(size_t)l*32768 + k*1024 + h*32 + o]
                     : eb2[(size_t)l*1024 + h*32 + o];
  w2t[g] = bfbits(v);
  if (g < N_NODES) deg[g] = 0;
  // w1p[l][nt][lane][j] = B-frag element B[k=(lane>>4)*8+j][n=nt*16+(lane&15)]
  // (zero for k>=16: K padded 16->32)
  if (g < 3*2*64*8) {
    int l2 = g >> 10;          // /1024
    int r2 = g & 1023;
    int nt = r2 >> 9;
    int ln = (r2 >> 3) & 63;
    int j  = r2 & 7;
    int kgr = ln >> 4;
    float w = (kgr < 2) ? ew1[(size_t)l2*512 + (kgr*8 + j)*32 + nt*16 + (ln & 15)] : 0.f;
    w1p[g] = bfbits(w);
  }
}

__global__ void k_hist(const int* __restrict__ ei, int* __restrict__ deg) {
  int t = blockIdx.x*256 + threadIdx.x;
  if (t >= N_EDGES) return;
  int d = ei[N_EDGES + t];
  d = min(max(d, 0), N_NODES-1);
  atomicAdd(&deg[d], 1);
}

__global__ __launch_bounds__(256) void k_scan1(const int* __restrict__ deg,
                                               int* __restrict__ off,
                                               int* __restrict__ bsum) {
  __shared__ int s[256];
  const int tid = threadIdx.x;
  const int t = blockIdx.x*256 + tid;
  int d = (t < N_NODES) ? deg[t] : 0;
  s[tid] = d; __syncthreads();
  int v = d;
  #pragma unroll
  for (int ofs = 1; ofs < 256; ofs <<= 1) {
    int w = (tid >= ofs) ? s[tid-ofs] : 0;
    __syncthreads();
    v += w; s[tid] = v;
    __syncthreads();
  }
  if (t < N_NODES) off[t] = v - d;
  if (tid == 255) bsum[blockIdx.x] = v;
}

__global__ __launch_bounds__(256) void k_scan2(int* __restrict__ bsum) {
  __shared__ int s[256];
  const int tid = threadIdx.x;
  int d = (tid < SCAN_BLOCKS) ? bsum[tid] : 0;
  s[tid] = d; __syncthreads();
  int v = d;
  #pragma unroll
  for (int ofs = 1; ofs < 256; ofs <<= 1) {
    int w = (tid >= ofs) ? s[tid-ofs] : 0;
    __syncthreads();
    v += w; s[tid] = v;
    __syncthreads();
  }
  if (tid < SCAN_BLOCKS) bsum[tid] = v - d;
}

__global__ void k_scan3(int* __restrict__ off, const int* __restrict__ bsum,
                        int* __restrict__ cursor) {
  int t = blockIdx.x*256 + threadIdx.x;
  if (t < N_NODES) {
    off[t] += bsum[t >> 8];
    cursor[t] = 0;
  }
  if (t == 0) off[N_NODES] = N_EDGES;
}

__global__ void k_scatter(const int* __restrict__ ei, const int* __restrict__ off,
                          int* __restrict__ cursor, int* __restrict__ elist) {
  int t = blockIdx.x*256 + threadIdx.x;
  if (t >= N_EDGES) return;
  int d = ei[N_EDGES + t];
  d = min(max(d, 0), N_NODES-1);
  int pos = atomicAdd(&cursor[d], 1);
  elist[off[d] + pos] = t;
}

// h = relu(x @ W + b)
__global__ void k_lin_in(const float* __restrict__ x,
                         const float* __restrict__ W,
                         const float* __restrict__ b,
                         float* __restrict__ h) {
  __shared__ float Ws[NODE_F*HID];
  __shared__ float bs[HID];
  for (int i = threadIdx.x; i < NODE_F*HID; i += 256) Ws[i] = W[i];
  if (threadIdx.x < HID) bs[threadIdx.x] = b[threadIdx.x];
  __syncthreads();
  int t = blockIdx.x*256 + threadIdx.x;
  if (t >= N_NODES*HID) return;
  int n = t >> 5, o = t & 31;
  const float4* xp = (const float4*)(x + (size_t)n*NODE_F);
  float acc = bs[o];
  #pragma unroll
  for (int j = 0; j < NODE_F/4; j++) {
    float4 v = xp[j];
    acc = fmaf(v.x, Ws[(4*j+0)*HID+o], acc);
    acc = fmaf(v.y, Ws[(4*j+1)*HID+o], acc);
    acc = fmaf(v.z, Ws[(4*j+2)*HID+o], acc);
    acc = fmaf(v.w, Ws[(4*j+3)*HID+o], acc);
  }
  h[t] = fmaxf(acc, 0.f);
}

// MFMA msg kernel. Per wave (fully independent, NO barrier):
//   1) he[32 edges,32] = relu(EA@W1+b1) via 4 MFMAs (K padded 16->32, quads 2-3 zero)
//   2) msg = P @ W2R main loop (depth-3 register pipeline), P built rank-1 on the fly.
__global__ __launch_bounds__(256) void k_msg(const float* __restrict__ hin,
                                             const float* __restrict__ ea,
                                             const int* __restrict__ ei,
                                             const unsigned short* __restrict__ w1pl,
                                             const float* __restrict__ b1,
                                             const unsigned short* __restrict__ w2tl,
                                             float* __restrict__ msg) {
  __shared__ float sHE[128*33];   // he[e][0..32], stride 33
  __shared__ int   sSRC[128];
  const int tid = threadIdx.x;
  const int be  = blockIdx.x*128;
  const int wv   = tid >> 6;          // wave 0..3
  const int lane = tid & 63;
  const int nn   = lane & 15;
  const int quad = lane >> 4;
  const int eb0  = wv*32;
  const int eb1  = wv*32 + 16;

  // per-wave src staging + bias K-row
  if (lane < 32) {
    int e = min(be + wv*32 + lane, N_EDGES-1);
    sSRC[wv*32 + lane] = min(max(ei[e], 0), N_NODES-1);
    sHE[(wv*32 + lane)*33 + 32] = 1.0f;
  }

  // --- he via MFMA ---
  {
    AFrag a0, a1;
    if (quad < 2) {
      int e0 = min(be + eb0 + nn, N_EDGES-1);
      int e1 = min(be + eb1 + nn, N_EDGES-1);
      const float4* p0 = (const float4*)(ea + (size_t)e0*EDGE_F + quad*8);
      const float4* p1 = (const float4*)(ea + (size_t)e1*EDGE_F + quad*8);
      float4 u = p0[0], v = p0[1];
      float4 s = p1[0], t = p1[1];
      a0.u[0] = pk2(f32x2{u.x,u.y}); a0.u[1] = pk2(f32x2{u.z,u.w});
      a0.u[2] = pk2(f32x2{v.x,v.y}); a0.u[3] = pk2(f32x2{v.z,v.w});
      a1.u[0] = pk2(f32x2{s.x,s.y}); a1.u[1] = pk2(f32x2{s.z,s.w});
      a1.u[2] = pk2(f32x2{t.x,t.y}); a1.u[3] = pk2(f32x2{t.z,t.w});
    } else {
      #pragma unroll
      for (int i = 0; i < 4; i++) { a0.u[i] = 0u; a1.u[i] = 0u; }
    }
    short8 wb0 = *(const short8*)(w1pl + lane*8);         // nt=0
    short8 wb1 = *(const short8*)(w1pl + 512 + lane*8);   // nt=1
    f32x4 z = {0.f,0.f,0.f,0.f};
    f32x4 h00 = __builtin_amdgcn_mfma_f32_16x16x32_bf16(a0.v, wb0, z, 0, 0, 0);
    f32x4 h01 = __builtin_amdgcn_mfma_f32_16x16x32_bf16(a0.v, wb1, z, 0, 0, 0);
    f32x4 h10 = __builtin_amdgcn_mfma_f32_16x16x32_bf16(a1.v, wb0, z, 0, 0, 0);
    f32x4 h11 = __builtin_amdgcn_mfma_f32_16x16x32_bf16(a1.v, wb1, z, 0, 0, 0);
    float bv0 = b1[nn], bv1 = b1[nn + 16];
    #pragma unroll
    for (int r = 0; r < 4; r++) {
      int ro0 = (eb0 + quad*4 + r)*33;
      int ro1 = (eb1 + quad*4 + r)*33;
      sHE[ro0 + nn]      = fmaxf(h00[r] + bv0, 0.f);
      sHE[ro0 + 16 + nn] = fmaxf(h01[r] + bv1, 0.f);
      sHE[ro1 + nn]      = fmaxf(h10[r] + bv0, 0.f);
      sHE[ro1 + 16 + nn] = fmaxf(h11[r] + bv1, 0.f);
    }
  }
  // no __syncthreads: all LDS producer/consumer pairs are wave-internal

  // xs straight from global (L2-hot)
  f32x2 xA[4], xB[4];
  {
    int s0i = sSRC[eb0+nn];
    int s1i = sSRC[eb1+nn];
    const float4* p0 = (const float4*)(hin + (size_t)s0i*HID);
    const float4* p1 = (const float4*)(hin + (size_t)s1i*HID);
    float4 a0 = p0[quad*2], a1 = p0[quad*2+1];
    float4 b0 = p1[quad*2], b1v = p1[quad*2+1];
    xA[0] = f32x2{a0.x, a0.y}; xA[1] = f32x2{a0.z, a0.w};
    xA[2] = f32x2{a1.x, a1.y}; xA[3] = f32x2{a1.z, a1.w};
    xB[0] = f32x2{b0.x, b0.y}; xB[1] = f32x2{b0.z, b0.w};
    xB[2] = f32x2{b1v.x, b1v.y}; xB[3] = f32x2{b1v.z, b1v.w};
  }

  f32x4 c00 = {0.f,0.f,0.f,0.f}, c01 = c00, c10 = c00, c11 = c00;
  const unsigned short* bp0 = w2tl + (unsigned)nn*KTOT + quad*8;
  const unsigned short* bp1 = bp0 + 16*KTOT;
  const float* heRow0 = sHE + (eb0+nn)*33;
  const float* heRow1 = sHE + (eb1+nn)*33;

  // depth-3 pipeline slots
  short8 sb0[3], sb1[3];
  float  sh0[3], sh1[3];
  #pragma unroll
  for (int j = 0; j < 3; j++) {
    sb0[j] = *(const short8*)(bp0 + j*32);
    sb1[j] = *(const short8*)(bp1 + j*32);
    sh0[j] = heRow0[j];
    sh1[j] = heRow1[j];
  }

  #pragma unroll 1
  for (int base = 0; base < 30; base += 3) {
    #pragma unroll
    for (int j = 0; j < 3; j++) {
      const int kk = base + j;
      float hk0 = sh0[j], hk1 = sh1[j];
      AFrag a0, a1;
      #pragma unroll
      for (int i = 0; i < 4; i++) {
        a0.u[i] = pk2(xA[i]*hk0);
        a1.u[i] = pk2(xB[i]*hk1);
      }
      short8 cb0 = sb0[j], cb1 = sb1[j];
      c00 = __builtin_amdgcn_mfma_f32_16x16x32_bf16(a0.v, cb0, c00, 0, 0, 0);
      c01 = __builtin_amdgcn_mfma_f32_16x16x32_bf16(a0.v, cb1, c01, 0, 0, 0);
      c10 = __builtin_amdgcn_mfma_f32_16x16x32_bf16(a1.v, cb0, c10, 0, 0, 0);
      c11 = __builtin_amdgcn_mfma_f32_16x16x32_bf16(a1.v, cb1, c11, 0, 0, 0);
      sb0[j] = *(const short8*)(bp0 + (kk+3)*32);
      sb1[j] = *(const short8*)(bp1 + (kk+3)*32);
      sh0[j] = heRow0[kk+3];
      sh1[j] = heRow1[kk+3];
    }
  }
  #pragma unroll
  for (int j = 0; j < 3; j++) {
    float hk0 = sh0[j], hk1 = sh1[j];
    AFrag a0, a1;
    #pragma unroll
    for (int i = 0; i < 4; i++) {
      a0.u[i] = pk2(xA[i]*hk0);
      a1.u[i] = pk2(xB[i]*hk1);
    }
    c00 = __builtin_amdgcn_mfma_f32_16x16x32_bf16(a0.v, sb0[j], c00, 0, 0, 0);
    c01 = __builtin_amdgcn_mfma_f32_16x16x32_bf16(a0.v, sb1[j], c01, 0, 0, 0);
    c10 = __builtin_amdgcn_mfma_f32_16x16x32_bf16(a1.v, sb0[j], c10, 0, 0, 0);
    c11 = __builtin_amdgcn_mfma_f32_16x16x32_bf16(a1.v, sb1[j], c11, 0, 0, 0);
  }

  #pragma unroll
  for (int r = 0; r < 4; r++) {
    int e0 = be + eb0 + quad*4 + r;
    if (e0 < N_EDGES) {
      msg[(size_t)e0*HID +      nn] = c00[r];
      msg[(size_t)e0*HID + 16 + nn] = c01[r];
    }
    int e1 = be + eb1 + quad*4 + r;
    if (e1 < N_EDGES) {
      msg[(size_t)e1*HID +      nn] = c10[r];
      msg[(size_t)e1*HID + 16 + nn] = c11[r];
    }
  }
}

// hout = relu( (sum_{e in CSR[n]} msg[e]) / max(deg,1) + hin @ root_w + root_b )
__global__ void k_gather(const float* __restrict__ msg,
                         const int* __restrict__ off, const int* __restrict__ elist,
                         const float* __restrict__ hin,
                         const float* __restrict__ rw,
                         const float* __restrict__ rb,
                         float* __restrict__ hout) {
  __shared__ float rws[HID*HID];
  __shared__ float rbs[HID];
  for (int i = threadIdx.x; i < HID*HID; i += 256) rws[i] = rw[i];
  if (threadIdx.x < HID) rbs[threadIdx.x] = rb[threadIdx.x];
  __syncthreads();
  int t = blockIdx.x*256 + threadIdx.x;
  if (t >= N_NODES*8) return;
  int n = t >> 3, oc = t & 7;
  int s0 = off[n], s1 = off[n+1];
  float a0 = 0.f, a1 = 0.f, a2 = 0.f, a3 = 0.f;
  for (int j = s0; j < s1; j++) {
    int e = elist[j];
    float4 v = ((const float4*)(msg + (size_t)e*HID))[oc];
    a0 += v.x; a1 += v.y; a2 += v.z; a3 += v.w;
  }
  float inv = 1.f / fmaxf((float)(s1 - s0), 1.f);
  a0 = fmaf(a0, inv, rbs[oc*4+0]);
  a1 = fmaf(a1, inv, rbs[oc*4+1]);
  a2 = fmaf(a2, inv, rbs[oc*4+2]);
  a3 = fmaf(a3, inv, rbs[oc*4+3]);
  const float4* hp = (const float4*)(hin + (size_t)n*HID);
  #pragma unroll
  for (int jq = 0; jq < 8; jq++) {
    float4 hv = hp[jq];
    #pragma unroll
    for (int c = 0; c < 4; c++) {
      int j = jq*4 + c;
      float h = (c==0)?hv.x:(c==1)?hv.y:(c==2)?hv.z:hv.w;
      const float4* rp = (const float4*)(rws + j*HID + oc*4);
      float4 r = rp[0];
      a0 = fmaf(h, r.x, a0);
      a1 = fmaf(h, r.y, a1);
      a2 = fmaf(h, r.z, a2);
      a3 = fmaf(h, r.w, a3);
    }
  }
  float4 res = make_float4(fmaxf(a0,0.f), fmaxf(a1,0.f), fmaxf(a2,0.f), fmaxf(a3,0.f));
  ((float4*)(hout + (size_t)n*HID))[oc] = res;
}

// out = (relu((h@lo_w+lo_b)@d1_w+d1_b))@d2_w+d2_b   (no relu on z)
__global__ void k_decoder(const float* __restrict__ h,
                          const float* __restrict__ lo_w, const float* __restrict__ lo_b,
                          const float* __restrict__ d1_w, const float* __restrict__ d1_b,
                          const float* __restrict__ d2_w, const float* __restrict__ d2_b,
                          float* __restrict__ out) {
  __shared__ float lows[HID*LAT], lobs[LAT], d1s[LAT*HID], d1bs[HID], d2s[HID*NODE_F], d2bs[NODE_F];
  for (int i = threadIdx.x; i < HID*LAT; i += 256) lows[i] = lo_w[i];
  for (int i = threadIdx.x; i < LAT; i += 256) lobs[i] = lo_b[i];
  for (int i = threadIdx.x; i < LAT*HID; i += 256) d1s[i] = d1_w[i];
  for (int i = threadIdx.x; i < HID; i += 256) d1bs[i] = d1_b[i];
  for (int i = threadIdx.x; i < HID*NODE_F; i += 256) d2s[i] = d2_w[i];
  for (int i = threadIdx.x; i < NODE_F; i += 256) d2bs[i] = d2_b[i];
  __syncthreads();
  int n = blockIdx.x*256 + threadIdx.x;
  if (n >= N_NODES) return;
  float hr[HID];
  const float4* hp = (const float4*)(h + (size_t)n*HID);
  #pragma unroll
  for (int i = 0; i < HID/4; i++) { float4 v = hp[i]; hr[4*i]=v.x; hr[4*i+1]=v.y; hr[4*i+2]=v.z; hr[4*i+3]=v.w; }
  float z[LAT];
  #pragma unroll
  for (int o = 0; o < LAT; o++) {
    float a = lobs[o];
    #pragma unroll
    for (int j = 0; j < HID; j++) a = fmaf(hr[j], lows[j*LAT+o], a);
    z[o] = a;
  }
  float d[HID];
  #pragma unroll
  for (int o = 0; o < HID; o++) {
    float a = d1bs[o];
    #pragma unroll
    for (int j = 0; j < LAT; j++) a = fmaf(z[j], d1s[j*HID+o], a);
    d[o] = fmaxf(a, 0.f);
  }
  float* op = out + (size_t)n*NODE_F;
  #pragma unroll 8
  for (int o = 0; o < NODE_F; o++) {
    float a = d2bs[o];
    #pragma unroll
    for (int j = 0; j < HID; j++) a = fmaf(d[j], d2s[j*NODE_F+o], a);
    op[o] = a;
  }
}

extern "C" void kernel_launch(void* const* d_in, const int* in_sizes, int n_in,
                              void* d_out, int out_size, void* d_ws, size_t ws_size,
                              hipStream_t stream) {
  const float* x   = (const float*)d_in[0];
  const int*   ei  = (const int*)d_in[1];
  const float* ea  = (const float*)d_in[2];
  const float* liw = (const float*)d_in[3];
  const float* lib = (const float*)d_in[4];
  const float* ew1 = (const float*)d_in[5];
  const float* eb1 = (const float*)d_in[6];
  const float* ew2 = (const float*)d_in[7];
  const float* eb2 = (const float*)d_in[8];
  const float* rw  = (const float*)d_in[9];
  const float* rb  = (const float*)d_in[10];
  const float* low = (const float*)d_in[11];
  const float* lob = (const float*)d_in[12];
  const float* d1w = (const float*)d_in[13];
  const float* d1b = (const float*)d_in[14];
  const float* d2w = (const float*)d_in[15];
  const float* d2b = (const float*)d_in[16];
  float* out = (float*)d_out;

  float* h0   = (float*)d_ws;                          // 1.6M f
  float* h1   = h0  + (size_t)N_NODES*HID;             // 1.6M f
  float* msg  = h1  + (size_t)N_NODES*HID;             // 6.4M f
  int*  deg   = (int*)(msg + (size_t)N_EDGES*HID);     // 50k
  int*  off   = deg + N_NODES;                         // 50k+1 (alloc 50016)
  int*  cursor= off + N_NODES + 16;                    // 50k
  int*  elist = cursor + N_NODES;                      // 200k
  int*  bsum  = elist + N_EDGES;                       // 256
  unsigned short* w2t = (unsigned short*)(bsum + 256); // 3*32*1056 bf16
  unsigned short* w1p = w2t + 3*HID*KTOT;              // 3*1024 bf16

  k_prep<<<(3*HID*KTOT)/256, 256, 0, stream>>>(ew2, eb2, ew1, w2t, w1p, deg);
  k_hist<<<(N_EDGES + 255)/256, 256, 0, stream>>>(ei, deg);
  k_scan1<<<SCAN_BLOCKS, 256, 0, stream>>>(deg, off, bsum);
  k_scan2<<<1, 256, 0, stream>>>(bsum);
  k_scan3<<<(N_NODES + 255)/256, 256, 0, stream>>>(off, bsum, cursor);
  k_scatter<<<(N_EDGES + 255)/256, 256, 0, stream>>>(ei, off, cursor, elist);

  k_lin_in<<<(N_NODES*HID + 255)/256, 256, 0, stream>>>(x, liw, lib, h0);

  float* hin = h0; float* hout = h1;
  for (int i = 0; i < 3; i++) {
    k_msg<<<(N_EDGES + 127)/128, 256, 0, stream>>>(hin, ea, ei,
        w1p + (size_t)i*1024, eb1 + i*HID,
        w2t + (size_t)i*HID*KTOT, msg);
    k_gather<<<(N_NODES*8 + 255)/256, 256, 0, stream>>>(msg, off, elist, hin,
        rw + i*HID*HID, rb + i*HID, hout);
    float* t = hin; hin = hout; hout = t;
  }

  k_decoder<<<(N_NODES + 255)/256, 256, 0, stream>>>(hin, low, lob, d1w, d1b, d2w, d2b, out);
}